// Round 10
// baseline (11328.701 us; speedup 1.0000x reference)
//
#include <hip/hip_runtime.h>
#include <hip/hip_bf16.h>

#define NB 32
#define TT 512
#define DD 20

using bf16x8 = __attribute__((ext_vector_type(8))) short;
using f32x4  = __attribute__((ext_vector_type(4))) float;

typedef __attribute__((address_space(3))) unsigned int lds_uint;
typedef __attribute__((address_space(1))) unsigned int glob_uint;

// ---- workspace offsets ----
#define OFF_WSTR  0          // 1,638,400 B weight stream (layout differs quad vs solo)
#define OFF_WPROJ 1638400
#define OFF_B0    1654784
#define OFF_B1    1658880
#define OFF_EXCH  1662976    // quad: 64 grps x 2 layers x 4 g x 4KB = 2MB
#define OFF_FLAG  3760128    // quad: 512 u32
#define WS_NEED_QUAD 3762176
#define WQUARTER  409600     // 25 panels x 4 wave-slices x 4KB
#define WSTR_BYTES 1638400

// ---- quad8 smem layout: 8 waves, 2-slot ring, red buffer ----
#define QM_H0    0        // 32*264*2 = 16896
#define QM_H1    16896
#define QM_XB    33792    // 2048
#define QM_WPS   35840    // 16384
#define QM_ZB    52224    // 4096
#define QM_RED   56320    // 4 khalf1 waves x 64 lanes x 132B = 33792 (cinit overlay here)
#define QM_RING  90112    // 8 waves x 2 slots x 4KB = 65536
#define QM_TOTAL 155648   // <= 160KB, 1 block/CU, 8 waves = 2/SIMD

// ---- solo smem layout (round-3 proven) ----
#define SM_RING  0
#define SM_H0    98304
#define SM_H1    115200
#define SM_XB    132096
#define SM_WPS   134144
#define SM_ZB    150528
#define SM_TOTAL 154624

__device__ __forceinline__ float sigf(float x) { return 1.0f / (1.0f + __expf(-x)); }
__device__ __forceinline__ float tanhfast(float x) { return 1.0f - 2.0f / (__expf(2.0f * x) + 1.0f); }

__device__ __forceinline__ void stage16(const char* g, const char* l) {
    __builtin_amdgcn_global_load_lds((glob_uint*)g, (lds_uint*)l, 16, 0, 0);
}

#define BARRIER_LK do { \
    asm volatile("s_waitcnt lgkmcnt(0)" ::: "memory"); \
    __builtin_amdgcn_s_barrier(); \
    asm volatile("" ::: "memory"); \
    __builtin_amdgcn_sched_barrier(0); \
} while (0)

// ================= QUAD PATH prep (unchanged stream layout) =================
// stream element: g*204800 + u*8192 + w4*2048 + q*512 + e2
// panels u: 0..7 W0h kt=u | 8 W0x | 9..16 W1h kt=u-9 | 17..24 W1x kt=u-17
// tile NT = q*16 + g*4 + w4
__global__ void prep_quad(const float* __restrict__ wih0, const float* __restrict__ whh0,
                          const float* __restrict__ wih1, const float* __restrict__ whh1,
                          const float* __restrict__ wproj,
                          const float* __restrict__ bih0, const float* __restrict__ bhh0,
                          const float* __restrict__ bih1, const float* __restrict__ bhh1,
                          char* __restrict__ ws) {
    int idx = blockIdx.x * 256 + threadIdx.x;
    if (idx < 819200) {
        int g  = idx / 204800;
        int r  = idx - g * 204800;
        int u  = r >> 13;
        int r2 = r & 8191;
        int w  = r2 >> 11;
        int r3 = r2 & 2047;
        int q  = r3 >> 9;
        int e2 = r3 & 511;
        const float* src; int K, kt;
        if (u < 8)       { src = whh0; K = 256; kt = u; }
        else if (u == 8) { src = wih0; K = 20;  kt = 0; }
        else if (u < 17) { src = whh1; K = 256; kt = u - 9; }
        else             { src = wih1; K = 256; kt = u - 17; }
        int NT = q * 16 + g * 4 + w;
        int j = e2 & 7, lane = e2 >> 3;
        int n = NT * 16 + (lane & 15);
        int k = kt * 32 + ((lane >> 4) << 3) + j;
        float v = (k < K) ? src[n * K + k] : 0.0f;
        ((__hip_bfloat16*)(ws + OFF_WSTR))[idx] = __float2bfloat16(v);
    } else if (idx < 827392) {
        int e = idx - 819200;
        int j = e & 7, lane = (e >> 3) & 63, tile = e >> 9;
        int kt = tile & 7, nt = tile >> 3;
        int n = nt * 16 + (lane & 15);
        int k = kt * 32 + ((lane >> 4) << 3) + j;
        float v = (n < 20) ? wproj[n * 256 + k] : 0.0f;
        ((__hip_bfloat16*)(ws + OFF_WPROJ))[e] = __float2bfloat16(v);
    } else if (idx < 828416) {
        int j = idx - 827392; ((float*)(ws + OFF_B0))[j] = bih0[j] + bhh0[j];
    } else if (idx < 829440) {
        int j = idx - 828416; ((float*)(ws + OFF_B1))[j] = bih1[j] + bhh1[j];
    } else if (idx < 829952) {
        ((unsigned int*)(ws + OFF_FLAG))[idx - 829440] = 0;
    }
}

// 256 blocks x 512 threads. grp=blockIdx&63, g=blockIdx>>6.
// Waves 0-3 (khalf0): even-kt panels, EW, exchange stores. Waves 4-7 (khalf1):
// odd-kt panels, phaseC, partial-acc -> red buffer. 2 waves/SIMD.
__global__ __launch_bounds__(512, 1) void decoder_quad8(
    const float* __restrict__ z, const float* __restrict__ w_lh, const float* __restrict__ b_lh,
    const float* __restrict__ w_lc, const float* __restrict__ b_lc,
    const float* __restrict__ b_proj, char* __restrict__ ws,
    float* __restrict__ out) {

    __shared__ __align__(16) char smem[QM_TOTAL];

    const int tid = threadIdx.x;
    const int grp = blockIdx.x & 63;
    const int g   = blockIdx.x >> 6;
    const int b0  = grp * NB;

    __hip_bfloat16* h0p = (__hip_bfloat16*)(smem + QM_H0);
    __hip_bfloat16* h1p = (__hip_bfloat16*)(smem + QM_H1);
    __hip_bfloat16* xbh = (__hip_bfloat16*)(smem + QM_XB);

    // ---- init: z, xb zero, W_proj ----
    {
        float* zbf = (float*)(smem + QM_ZB);
        zbf[tid]       = z[(b0 + (tid >> 5)) * 32 + (tid & 31)];
        int i2 = tid + 512;
        zbf[i2]        = z[(b0 + (i2 >> 5)) * 32 + (i2 & 31)];
        ((unsigned int*)(smem + QM_XB))[tid] = 0;
        const bf16x8* sp = (const bf16x8*)(ws + OFF_WPROJ);
        bf16x8* dp = (bf16x8*)(smem + QM_WPS);
        dp[tid] = sp[tid];
        dp[tid + 512] = sp[tid + 512];
    }
    __syncthreads();

    // ---- h/c init (overlay at QM_RED, 64KB spans RED+RING head) ----
    {
        float* cinitf = (float*)(smem + QM_RED);
        const float* zbf = (const float*)(smem + QM_ZB);
        for (int ii = 0; ii < 32; ii++) {
            int pi = ii * 512 + tid;
            int b = pi >> 9, col = pi & 511;
            float dh = b_lh[col], dc = b_lc[col];
            #pragma unroll 8
            for (int k = 0; k < 32; k++) {
                float zv = zbf[b * 32 + k];
                dh += zv * w_lh[col * 32 + k];
                dc += zv * w_lc[col * 32 + k];
            }
            if (col < 256) { h0p[b * 264 + col]         = __float2bfloat16(dh); cinitf[b * 256 + col]                 = dc; }
            else           { h1p[b * 264 + (col - 256)] = __float2bfloat16(dh); cinitf[8192 + b * 256 + (col - 256)] = dc; }
        }
    }
    __syncthreads();

    const int w   = tid >> 6, ln = tid & 63;
    const int wlo = w & 3;                       // gate-col-tile
    const int l15 = ln & 15, lq = ln >> 4;
    const int lnoff = ln * 16;
    const int colg = g * 64 + wlo * 16 + l15;    // owned h-col (khalf0 semantics)

    // c-state only on khalf0 waves
    float c0r[2][4], c1r[2][4];
    if (w < 4) {
        const float* cinitf = (const float*)(smem + QM_RED);
        #pragma unroll
        for (int mt = 0; mt < 2; mt++)
            #pragma unroll
            for (int r = 0; r < 4; r++) {
                int m = mt * 16 + lq * 4 + r;
                c0r[mt][r] = cinitf[m * 256 + colg];
                c1r[mt][r] = cinitf[8192 + m * 256 + colg];
            }
    }
    __syncthreads();   // overlay dead; ring staging may start

    const float* bias0 = (const float*)(ws + OFF_B0);
    const float* bias1 = (const float*)(ws + OFF_B1);
    float bs0[4], bs1[4];
    #pragma unroll
    for (int q = 0; q < 4; q++) {
        bs0[q] = bias0[q * 256 + colg];
        bs1[q] = bias1[q * 256 + colg];
    }
    // phaseC on khalf1 waves: pcw = w&3
    const int pc_nt = wlo & 1, pc_mt = wlo >> 1;
    const int pc_col = pc_nt * 16 + l15;
    const float bpj = (w >= 4 && pc_col < 20) ? b_proj[pc_col] : 0.0f;

    const char* wps_c = smem + QM_WPS;
    const char* h0c = smem + QM_H0;
    const char* h1c = smem + QM_H1;
    const char* xbc = smem + QM_XB;
    float* outp = out;

    const char* wgl   = ws + OFF_WSTR + g * WQUARTER + wlo * 4096 + lnoff;
    char*       ringb = smem + QM_RING + w * 8192;            // 2 slots x 4KB
    const char* ringc = smem + QM_RING + w * 8192 + lnoff;
    int slS = 0, slR = 0;

    f32x4 acc[4][2];
    bf16x8 wT0, wT1, wT2, wT3, afA, afB;

#define STAGE_U(u) do { \
    const char* gs_ = wgl + (u) * 16384; \
    char* ld_ = ringb + slS * 4096; \
    stage16(gs_,        ld_); \
    stage16(gs_ + 1024, ld_ + 1024); \
    stage16(gs_ + 2048, ld_ + 2048); \
    stage16(gs_ + 3072, ld_ + 3072); \
    slS ^= 1; \
} while (0)

#define WWAIT do { \
    asm volatile("s_waitcnt vmcnt(4)" ::: "memory"); \
    __builtin_amdgcn_sched_barrier(0); \
} while (0)

#define LOADW do { \
    const char* rb_ = ringc + slR * 4096; slR ^= 1; \
    wT0 = *(const bf16x8*)(rb_); \
    wT1 = *(const bf16x8*)(rb_ + 1024); \
    wT2 = *(const bf16x8*)(rb_ + 2048); \
    wT3 = *(const bf16x8*)(rb_ + 3072); \
} while (0)

#define LOADA(hsrc, ktv) do { \
    afA = *(const bf16x8*)((hsrc) + l15 * 528 + (ktv) * 64 + lq * 16); \
    afB = *(const bf16x8*)((hsrc) + (16 + l15) * 528 + (ktv) * 64 + lq * 16); \
} while (0)

#define LOADAX do { \
    afA = *(const bf16x8*)(xbc + l15 * 64 + lq * 16); \
    afB = *(const bf16x8*)(xbc + (16 + l15) * 64 + lq * 16); \
} while (0)

#define MFMA8 do { \
    acc[0][0] = __builtin_amdgcn_mfma_f32_16x16x32_bf16(afA, wT0, acc[0][0], 0, 0, 0); \
    acc[0][1] = __builtin_amdgcn_mfma_f32_16x16x32_bf16(afB, wT0, acc[0][1], 0, 0, 0); \
    acc[1][0] = __builtin_amdgcn_mfma_f32_16x16x32_bf16(afA, wT1, acc[1][0], 0, 0, 0); \
    acc[1][1] = __builtin_amdgcn_mfma_f32_16x16x32_bf16(afB, wT1, acc[1][1], 0, 0, 0); \
    acc[2][0] = __builtin_amdgcn_mfma_f32_16x16x32_bf16(afA, wT2, acc[2][0], 0, 0, 0); \
    acc[2][1] = __builtin_amdgcn_mfma_f32_16x16x32_bf16(afB, wT2, acc[2][1], 0, 0, 0); \
    acc[3][0] = __builtin_amdgcn_mfma_f32_16x16x32_bf16(afA, wT3, acc[3][0], 0, 0, 0); \
    acc[3][1] = __builtin_amdgcn_mfma_f32_16x16x32_bf16(afB, wT3, acc[3][1], 0, 0, 0); \
} while (0)

// panel: wait own oldest panel, read its tiles+afrag, 8 MFMA, stage 2-ahead.
// STAGE after MFMA8: the MFMA's lgkm wait proves the slot's ds_reads finished,
// so overwriting the just-consumed slot (2-slot ring) is safe.
#define DOP(hsrc, ktv, uNext) do { \
    WWAIT; LOADW; LOADA(hsrc, ktv); MFMA8; \
    __builtin_amdgcn_sched_barrier(0); \
    STAGE_U(uNext); \
} while (0)

#define DOPX(uNext) do { \
    WWAIT; LOADW; LOADAX; MFMA8; \
    __builtin_amdgcn_sched_barrier(0); \
    STAGE_U(uNext); \
} while (0)

#define ACC_SET(b_) do { _Pragma("unroll") for (int q = 0; q < 4; q++) { \
    f32x4 v_ = {(b_)[q], (b_)[q], (b_)[q], (b_)[q]}; acc[q][0] = v_; acc[q][1] = v_; } } while (0)
#define ACC_ZERO do { _Pragma("unroll") for (int q = 0; q < 4; q++) { \
    f32x4 v_ = {0.f, 0.f, 0.f, 0.f}; acc[q][0] = v_; acc[q][1] = v_; } } while (0)

    // red buffer: khalf1 wave wlo region, thread ln at +ln*132 (pad -> 2 lanes/bank)
    char* redme = smem + QM_RED + wlo * 8448 + ln * 132;

    auto redWrite = [&]() {
        #pragma unroll
        for (int c = 0; c < 8; c++)
            *(f32x4*)(redme + c * 16) = acc[c >> 1][c & 1];
    };
    auto redAdd = [&]() {
        #pragma unroll
        for (int c = 0; c < 8; c++) {
            f32x4 pv = *(const f32x4*)(redme + c * 16);
            acc[c >> 1][c & 1] += pv;
        }
    };

    auto phaseC = [&](int t) {
        f32x4 py = {bpj, bpj, bpj, bpj};
        #pragma unroll
        for (int kt = 0; kt < 8; kt++) {
            bf16x8 ah = *(const bf16x8*)(h1c + (pc_mt * 16 + l15) * 528 + kt * 64 + lq * 16);
            bf16x8 wf = *(const bf16x8*)(wps_c + pc_nt * 8192 + kt * 1024 + lnoff);
            py = __builtin_amdgcn_mfma_f32_16x16x32_bf16(ah, wf, py, 0, 0, 0);
        }
        if (pc_col < 20) {
            #pragma unroll
            for (int r = 0; r < 4; r++) {
                int row = pc_mt * 16 + lq * 4 + r;
                if (g == 0)
                    outp[((size_t)(b0 + row) * TT + (t - 1)) * DD + pc_col] = py[r];
                xbh[row * 32 + pc_col] = __float2bfloat16(py[r]);
            }
        }
    };

    unsigned int* exBase = (unsigned int*)(ws + OFF_EXCH);
    unsigned int* flBase = (unsigned int*)(ws + OFF_FLAG);

    // store own 4KB h-slice (khalf0 waves only: tid<256, vmcnt(0) drain local to them)
    auto exchStore = [&](int L, const char* hp, int t) {
        if (w < 4) {
            unsigned int* exO = exBase + ((grp * 2 + L) * 4 + g) * 1024;
            unsigned int* flO = flBase + (grp * 2 + L) * 4 + g;
            #pragma unroll
            for (int i = 0; i < 4; i++) {
                int wi = tid * 4 + i, m = wi >> 5, cp = wi & 31;
                unsigned int v = *(const unsigned int*)(hp + m * 528 + g * 128 + cp * 4);
                __hip_atomic_store(&exO[wi], v, __ATOMIC_RELAXED, __HIP_MEMORY_SCOPE_AGENT);
            }
            asm volatile("s_waitcnt vmcnt(0)" ::: "memory");
            if (tid == 0)
                __hip_atomic_store(flO, (unsigned int)(t + 1), __ATOMIC_RELAXED, __HIP_MEMORY_SCOPE_AGENT);
        }
    };

    // finish: wait 3 partner flags, gather 3x4KB into LDS (all 512 threads, 2 u32 each/partner)
    auto exchFinish = [&](int L, char* hp, unsigned int expect) {
        if (tid < 3) {
            int p = tid + (tid >= g);
            unsigned int* flP = flBase + (grp * 2 + L) * 4 + p;
            int spins = 0;
            while (__hip_atomic_load(flP, __ATOMIC_RELAXED, __HIP_MEMORY_SCOPE_AGENT) < expect) {
                __builtin_amdgcn_s_sleep(8);
                if (++spins > (1 << 11)) break;   // desync -> fast wrong answer, not hang
            }
        }
        BARRIER_LK;
        #pragma unroll
        for (int pp = 0; pp < 3; pp++) {
            int p = pp + (pp >= g);
            unsigned int* exP = exBase + ((grp * 2 + L) * 4 + p) * 1024;
            unsigned int pv[2];
            #pragma unroll
            for (int i = 0; i < 2; i++)
                pv[i] = __hip_atomic_load(&exP[tid * 2 + i], __ATOMIC_RELAXED, __HIP_MEMORY_SCOPE_AGENT);
            #pragma unroll
            for (int i = 0; i < 2; i++) {
                int wi = tid * 2 + i, m = wi >> 5, cp = wi & 31;
                *(unsigned int*)(hp + m * 528 + p * 128 + cp * 4) = pv[i];
            }
        }
        BARRIER_LK;
    };

    // ---- prologue: each wave stages its first two panels ----
    if (w < 4) { STAGE_U(0); STAGE_U(2); }
    else       { STAGE_U(1); STAGE_U(3); }

    #pragma unroll 1
    for (int t = 0; t < TT; t++) {
        // ======== phase A partials: W0h ========
        if (w < 4) {
            ACC_SET(bs0);
            DOP(h0c, 0, 4); DOP(h0c, 2, 6); DOP(h0c, 4, 8); DOP(h0c, 6, 9);
        } else {
            ACC_ZERO;
            DOP(h0c, 1, 5); DOP(h0c, 3, 7); DOP(h0c, 5, 10); DOP(h0c, 7, 12);
        }
        if (t > 0) {
            exchFinish(1, (char*)(smem + QM_H1), (unsigned int)t);  // h1(t-1) full
            if (w >= 4) phaseC(t);                                   // y(t-1), xb(t)
        }
        BARRIER_LK;   // B1: xbh visible
        if (w < 4) {
            DOPX(11);                          // u=8: x @ W0x (full x-contribution)
        } else {
            redWrite();                        // gates0 odd-kt partial -> red
            ACC_ZERO;
            DOP(h1c, 1, 14);                   // u=10: W1h kt1 (h1(t-1) full)
        }
        BARRIER_LK;   // B2: red visible
        if (w < 4) {
            redAdd();                          // full gates0
            #pragma unroll
            for (int mt = 0; mt < 2; mt++)
                #pragma unroll
                for (int r = 0; r < 4; r++) {
                    float iv = acc[0][mt][r], fv = acc[1][mt][r];
                    float gv = acc[2][mt][r], ov = acc[3][mt][r];
                    float cn = sigf(fv) * c0r[mt][r] + sigf(iv) * tanhfast(gv);
                    float hn = sigf(ov) * tanhfast(cn);
                    c0r[mt][r] = cn;
                    h0p[(mt * 16 + lq * 4 + r) * 264 + colg] = __float2bfloat16(hn);
                }
            ACC_SET(bs1);
        } else {
            DOP(h1c, 3, 16);                   // u=12: W1h kt3
        }
        BARRIER_LK;   // B3: h0p own slice visible
        exchStore(0, h0c, t);                  // post h0(t)

        // ======== phase B partials: W1h ========
        if (w < 4) {
            DOP(h1c, 0, 13); DOP(h1c, 2, 15); DOP(h1c, 4, 17); DOP(h1c, 6, 19);
        } else {
            DOP(h1c, 5, 18); DOP(h1c, 7, 20);
        }
        exchFinish(0, (char*)(smem + QM_H0), (unsigned int)(t + 1));  // h0(t) full

        // ======== W1x ========
        if (w < 4) {
            DOP(h0c, 0, 21); DOP(h0c, 2, 23); DOP(h0c, 4, 0); DOP(h0c, 6, 2);
        } else {
            DOP(h0c, 1, 22); DOP(h0c, 3, 24); DOP(h0c, 5, 1); DOP(h0c, 7, 3);
            redWrite();                        // gates1 odd-kt partial -> red
        }
        BARRIER_LK;   // B4: red visible
        if (w < 4) {
            redAdd();                          // full gates1
            #pragma unroll
            for (int mt = 0; mt < 2; mt++)
                #pragma unroll
                for (int r = 0; r < 4; r++) {
                    float iv = acc[0][mt][r], fv = acc[1][mt][r];
                    float gv = acc[2][mt][r], ov = acc[3][mt][r];
                    float cn = sigf(fv) * c1r[mt][r] + sigf(iv) * tanhfast(gv);
                    float hn = sigf(ov) * tanhfast(cn);
                    c1r[mt][r] = cn;
                    h1p[(mt * 16 + lq * 4 + r) * 264 + colg] = __float2bfloat16(hn);
                }
        }
        BARRIER_LK;   // B5: h1p own slice visible
        exchStore(1, h1c, t);                  // post h1(t)
    }

    exchFinish(1, (char*)(smem + QM_H1), (unsigned int)TT);
    if (w >= 4) phaseC(TT);

#undef STAGE_U
#undef WWAIT
#undef LOADW
#undef LOADA
#undef LOADAX
#undef MFMA8
#undef DOP
#undef DOPX
#undef ACC_SET
#undef ACC_ZERO
}

// ================= SOLO FALLBACK (round-3 proven kernel, 64 blocks) =================

__global__ void prep_solo(const float* __restrict__ wih0, const float* __restrict__ whh0,
                          const float* __restrict__ wih1, const float* __restrict__ whh1,
                          const float* __restrict__ wproj,
                          const float* __restrict__ bih0, const float* __restrict__ bhh0,
                          const float* __restrict__ bih1, const float* __restrict__ bhh1,
                          char* __restrict__ ws) {
    int idx = blockIdx.x * 256 + threadIdx.x;
    if (idx < 819200) {
        int s  = idx >> 12;
        int wv = (idx >> 9) & 7;
        int e2 = idx & 511;
        int u = s >> 2, qq = s & 3, half = u & 1;
        const float* src; int K, kt;
        if (u < 16)      { src = whh0; K = 256; kt = u >> 1; }
        else if (u < 18) { src = wih0; K = 20;  kt = 0; }
        else if (u < 34) { src = wih1; K = 256; kt = (u - 18) >> 1; }
        else             { src = whh1; K = 256; kt = (u - 34) >> 1; }
        int NT = half * 32 + (qq >> 1) * 16 + wv * 2 + (qq & 1);
        int j = e2 & 7, lane = e2 >> 3;
        int n = NT * 16 + (lane & 15);
        int k = kt * 32 + ((lane >> 4) << 3) + j;
        float v = (k < K) ? src[n * K + k] : 0.0f;
        ((__hip_bfloat16*)(ws + OFF_WSTR))[idx] = __float2bfloat16(v);
    } else if (idx < 827392) {
        int e = idx - 819200;
        int j = e & 7, lane = (e >> 3) & 63, tile = e >> 9;
        int kt = tile & 7, nt = tile >> 3;
        int n = nt * 16 + (lane & 15);
        int k = kt * 32 + ((lane >> 4) << 3) + j;
        float v = (n < 20) ? wproj[n * 256 + k] : 0.0f;
        ((__hip_bfloat16*)(ws + OFF_WPROJ))[e] = __float2bfloat16(v);
    } else if (idx < 828416) {
        int j = idx - 827392; ((float*)(ws + OFF_B0))[j] = bih0[j] + bhh0[j];
    } else if (idx < 829440) {
        int j = idx - 828416; ((float*)(ws + OFF_B1))[j] = bih1[j] + bhh1[j];
    }
}

__global__ __launch_bounds__(512, 1) void decoder_solo(
    const float* __restrict__ z, const float* __restrict__ w_lh, const float* __restrict__ b_lh,
    const float* __restrict__ w_lc, const float* __restrict__ b_lc,
    const float* __restrict__ b_proj, const char* __restrict__ ws,
    float* __restrict__ out) {

    __shared__ __align__(16) char smem[SM_TOTAL];

    const int tid = threadIdx.x;
    const int b0  = blockIdx.x * NB;

    __hip_bfloat16* h0p = (__hip_bfloat16*)(smem + SM_H0);
    __hip_bfloat16* h1p = (__hip_bfloat16*)(smem + SM_H1);
    __hip_bfloat16* xbh = (__hip_bfloat16*)(smem + SM_XB);

    {
        float* zbf = (float*)(smem + SM_ZB);
        zbf[tid]       = z[(b0 + (tid >> 5)) * 32 + (tid & 31)];
        int i2 = tid + 512;
        zbf[i2]        = z[(b0 + (i2 >> 5)) * 32 + (i2 & 31)];
        ((unsigned int*)(smem + SM_XB))[tid] = 0;
        const bf16x8* sp = (const bf16x8*)(ws + OFF_WPROJ);
        bf16x8* dp = (bf16x8*)(smem + SM_WPS);
        dp[tid] = sp[tid];
        dp[tid + 512] = sp[tid + 512];
    }
    __syncthreads();

    {
        float* cinitf = (float*)smem;
        const float* zbf = (const float*)(smem + SM_ZB);
        for (int ii = 0; ii < 32; ii++) {
            int pi = ii * 512 + tid;
            int b = pi >> 9, col = pi & 511;
            float dh = b_lh[col], dc = b_lc[col];
            #pragma unroll 8
            for (int k = 0; k < 32; k++) {
                float zv = zbf[b * 32 + k];
                dh += zv * w_lh[col * 32 + k];
                dc += zv * w_lc[col * 32 + k];
            }
            if (col < 256) { h0p[b * 264 + col]         = __float2bfloat16(dh); cinitf[b * 256 + col]                 = dc; }
            else           { h1p[b * 264 + (col - 256)] = __float2bfloat16(dh); cinitf[8192 + b * 256 + (col - 256)] = dc; }
        }
    }
    __syncthreads();

    const int wv = tid >> 6, ln = tid & 63;
    const int l15 = ln & 15, lq = ln >> 4;
    const int lnoff = ln * 16;

    float c0r[2][2][4], c1r[2][2][4];
    {
        const float* cinitf = (const float*)smem;
        #pragma unroll
        for (int mt = 0; mt < 2; mt++)
            #pragma unroll
            for (int h = 0; h < 2; h++)
                #pragma unroll
                for (int r = 0; r < 4; r++) {
                    int m = mt * 16 + lq * 4 + r, u = wv * 32 + h * 16 + l15;
                    c0r[mt][h][r] = cinitf[m * 256 + u];
                    c1r[mt][h][r] = cinitf[8192 + m * 256 + u];
                }
    }
    __syncthreads();

    const float* bias0 = (const float*)(ws + OFF_B0);
    const float* bias1 = (const float*)(ws + OFF_B1);
    float bs0[8], bs1[8];
    #pragma unroll
    for (int q = 0; q < 8; q++) {
        int col = (q >> 1) * 256 + wv * 32 + (q & 1) * 16 + l15;
        bs0[q] = bias0[col];
        bs1[q] = bias1[col];
    }
    const int pc_nt = wv & 1, pc_mt = wv >> 1;
    const int pc_col = pc_nt * 16 + l15;
    const float bpj = (wv < 4 && pc_col < 20) ? b_proj[pc_col] : 0.0f;

    const char* wps_c = smem + SM_WPS;
    const char* h0c = smem + SM_H0;
    const char* h1c = smem + SM_H1;
    const char* xbc = smem + SM_XB;

    float* outp = out;

    const char* wgl   = ws + OFF_WSTR + wv * 1024 + lnoff;
    char*       ringb = smem + SM_RING + wv * 12288;
    const char* ringc = smem + SM_RING + wv * 12288 + lnoff;
    int sOff = 2 * 32768;
    int slS  = 2;
    int slR  = 0;

    f32x4 acc[8][2];

    auto doPanel = [&](const char* hsrc, int kt, bool isX, int qbase) {
        bf16x8 af0, af1;
        if (isX) {
            af0 = *(const bf16x8*)(xbc + l15 * 64 + lq * 16);
            af1 = *(const bf16x8*)(xbc + (16 + l15) * 64 + lq * 16);
        } else {
            af0 = *(const bf16x8*)(hsrc + l15 * 528 + kt * 64 + lq * 16);
            af1 = *(const bf16x8*)(hsrc + (16 + l15) * 528 + kt * 64 + lq * 16);
        }
        #pragma unroll
        for (int j = 0; j < 4; j++)
            stage16(wgl + (sOff + j * 8192), ringb + slS * 4096 + j * 1024);
        sOff += 32768; if (sOff >= WSTR_BYTES) sOff = 0;
        slS = (slS == 2) ? 0 : slS + 1;
        asm volatile("s_waitcnt vmcnt(8)" ::: "memory");
        __builtin_amdgcn_sched_barrier(0);
        const char* rb = ringc + slR * 4096;
        slR = (slR == 2) ? 0 : slR + 1;
        bf16x8 w0 = *(const bf16x8*)(rb);
        bf16x8 w1 = *(const bf16x8*)(rb + 1024);
        bf16x8 w2 = *(const bf16x8*)(rb + 2048);
        bf16x8 w3 = *(const bf16x8*)(rb + 3072);
        acc[qbase + 0][0] = __builtin_amdgcn_mfma_f32_16x16x32_bf16(af0, w0, acc[qbase + 0][0], 0, 0, 0);
        acc[qbase + 0][1] = __builtin_amdgcn_mfma_f32_16x16x32_bf16(af1, w0, acc[qbase + 0][1], 0, 0, 0);
        acc[qbase + 1][0] = __builtin_amdgcn_mfma_f32_16x16x32_bf16(af0, w1, acc[qbase + 1][0], 0, 0, 0);
        acc[qbase + 1][1] = __builtin_amdgcn_mfma_f32_16x16x32_bf16(af1, w1, acc[qbase + 1][1], 0, 0, 0);
        acc[qbase + 2][0] = __builtin_amdgcn_mfma_f32_16x16x32_bf16(af0, w2, acc[qbase + 2][0], 0, 0, 0);
        acc[qbase + 2][1] = __builtin_amdgcn_mfma_f32_16x16x32_bf16(af1, w2, acc[qbase + 2][1], 0, 0, 0);
        acc[qbase + 3][0] = __builtin_amdgcn_mfma_f32_16x16x32_bf16(af0, w3, acc[qbase + 3][0], 0, 0, 0);
        acc[qbase + 3][1] = __builtin_amdgcn_mfma_f32_16x16x32_bf16(af1, w3, acc[qbase + 3][1], 0, 0, 0);
    };

    auto phaseC = [&](int t) {
        f32x4 py = {bpj, bpj, bpj, bpj};
        #pragma unroll
        for (int kt = 0; kt < 8; kt++) {
            bf16x8 ah = *(const bf16x8*)(h1c + (pc_mt * 16 + l15) * 528 + kt * 64 + lq * 16);
            bf16x8 wf = *(const bf16x8*)(wps_c + pc_nt * 8192 + kt * 1024 + lnoff);
            py = __builtin_amdgcn_mfma_f32_16x16x32_bf16(ah, wf, py, 0, 0, 0);
        }
        if (pc_col < 20) {
            #pragma unroll
            for (int r = 0; r < 4; r++) {
                int row = pc_mt * 16 + lq * 4 + r;
                outp[((size_t)(b0 + row) * TT + (t - 1)) * DD + pc_col] = py[r];
                xbh[row * 32 + pc_col] = __float2bfloat16(py[r]);
            }
        }
    };

    #pragma unroll
    for (int j = 0; j < 4; j++) stage16(wgl + j * 8192,         ringb + j * 1024);
    #pragma unroll
    for (int j = 0; j < 4; j++) stage16(wgl + 32768 + j * 8192, ringb + 4096 + j * 1024);

    #pragma unroll 1
    for (int t = 0; t < TT; t++) {
        #pragma unroll
        for (int q = 0; q < 8; q++) {
            f32x4 v = {bs0[q], bs0[q], bs0[q], bs0[q]};
            acc[q][0] = v; acc[q][1] = v;
        }
        if (t > 0 && wv < 4) phaseC(t);
        #pragma unroll 1
        for (int uu = 0; uu < 7; uu++) {
            doPanel(h0c, uu, false, 0);
            doPanel(h0c, uu, false, 4);
        }
        BARRIER_LK;
        doPanel(h0c, 7, false, 0);
        doPanel(h0c, 7, false, 4);
        doPanel(xbc, 0, true,  0);
        doPanel(xbc, 0, true,  4);
        BARRIER_LK;

        #pragma unroll
        for (int mt = 0; mt < 2; mt++)
            #pragma unroll
            for (int h = 0; h < 2; h++)
                #pragma unroll
                for (int r = 0; r < 4; r++) {
                    float iv = acc[0 + h][mt][r], fv = acc[2 + h][mt][r];
                    float gv = acc[4 + h][mt][r], ov = acc[6 + h][mt][r];
                    float cn = sigf(fv) * c0r[mt][h][r] + sigf(iv) * tanhfast(gv);
                    float hn = sigf(ov) * tanhfast(cn);
                    c0r[mt][h][r] = cn;
                    h0p[(mt * 16 + lq * 4 + r) * 264 + wv * 32 + h * 16 + l15] = __float2bfloat16(hn);
                }
        BARRIER_LK;

        #pragma unroll
        for (int q = 0; q < 8; q++) {
            f32x4 v = {bs1[q], bs1[q], bs1[q], bs1[q]};
            acc[q][0] = v; acc[q][1] = v;
        }
        #pragma unroll 1
        for (int uu = 0; uu < 8; uu++) {
            doPanel(h0c, uu, false, 0);
            doPanel(h0c, uu, false, 4);
        }
        #pragma unroll 1
        for (int uu = 0; uu < 8; uu++) {
            doPanel(h1c, uu, false, 0);
            doPanel(h1c, uu, false, 4);
        }
        BARRIER_LK;

        #pragma unroll
        for (int mt = 0; mt < 2; mt++)
            #pragma unroll
            for (int h = 0; h < 2; h++)
                #pragma unroll
                for (int r = 0; r < 4; r++) {
                    float iv = acc[0 + h][mt][r], fv = acc[2 + h][mt][r];
                    float gv = acc[4 + h][mt][r], ov = acc[6 + h][mt][r];
                    float cn = sigf(fv) * c1r[mt][h][r] + sigf(iv) * tanhfast(gv);
                    float hn = sigf(ov) * tanhfast(cn);
                    c1r[mt][h][r] = cn;
                    h1p[(mt * 16 + lq * 4 + r) * 264 + wv * 32 + h * 16 + l15] = __float2bfloat16(hn);
                }
        BARRIER_LK;
    }

    if (wv < 4) phaseC(TT);
}

// ================= launcher =================

extern "C" void kernel_launch(void* const* d_in, const int* in_sizes, int n_in,
                              void* d_out, int out_size, void* d_ws, size_t ws_size,
                              hipStream_t stream) {
    const float* z      = (const float*)d_in[0];
    const float* w_lh   = (const float*)d_in[3];
    const float* b_lh   = (const float*)d_in[4];
    const float* w_lc   = (const float*)d_in[5];
    const float* b_lc   = (const float*)d_in[6];
    const float* w_ih0  = (const float*)d_in[7];
    const float* w_hh0  = (const float*)d_in[8];
    const float* b_ih0  = (const float*)d_in[9];
    const float* b_hh0  = (const float*)d_in[10];
    const float* w_ih1  = (const float*)d_in[11];
    const float* w_hh1  = (const float*)d_in[12];
    const float* b_ih1  = (const float*)d_in[13];
    const float* b_hh1  = (const float*)d_in[14];
    const float* w_proj = (const float*)d_in[15];
    const float* b_proj = (const float*)d_in[16];
    char* ws = (char*)d_ws;
    float* out = (float*)d_out;

    if (ws_size >= (size_t)WS_NEED_QUAD) {
        prep_quad<<<3242, 256, 0, stream>>>(w_ih0, w_hh0, w_ih1, w_hh1, w_proj,
                                            b_ih0, b_hh0, b_ih1, b_hh1, ws);
        decoder_quad8<<<256, 512, 0, stream>>>(z, w_lh, b_lh, w_lc, b_lc, b_proj, ws, out);
    } else {
        prep_solo<<<3240, 256, 0, stream>>>(w_ih0, w_hh0, w_ih1, w_hh1, w_proj,
                                            b_ih0, b_hh0, b_ih1, b_hh1, ws);
        decoder_solo<<<64, 512, 0, stream>>>(z, w_lh, b_lh, w_lc, b_lc, b_proj, ws, out);
    }
}

// Round 12
// 6170.973 us; speedup vs baseline: 1.8358x; 1.8358x over previous
//
#include <hip/hip_runtime.h>
#include <hip/hip_bf16.h>

#define NB 32
#define TT 512
#define DD 20

using bf16x8 = __attribute__((ext_vector_type(8))) short;
using f32x4  = __attribute__((ext_vector_type(4))) float;

typedef __attribute__((address_space(3))) unsigned int lds_uint;
typedef __attribute__((address_space(1))) unsigned int glob_uint;

// ---- workspace offsets ----
#define OFF_WSTR  0          // 1,638,400 B weight stream (layout differs quad vs solo)
#define OFF_WPROJ 1638400
#define OFF_B0    1654784
#define OFF_B1    1658880
#define OFF_EXCH  1662976    // quad: 64 grps x 2 layers x 4 g x 4KB = 2MB
#define OFF_FLAG  3760128    // quad: 512 u32
#define WS_NEED_QUAD 3762176
#define WQUARTER  409600     // 25 panels x 4 waves x 4KB
#define WSTR_BYTES 1638400

// ---- quad smem layout: ring depth 4 (16KB/wave x 4 waves = 64KB) ----
#define QM_H0    0        // 32*264*2 = 16896
#define QM_H1    16896
#define QM_XB    33792    // 2048
#define QM_WPS   35840    // 16384
#define QM_ZB    52224    // 4096
#define QM_RING  56320    // 4 waves x 4 slots x 4KB = 65536 (cinit 64K overlay here)
#define QM_TOTAL 121856

// ---- solo smem layout (round-3 proven) ----
#define SM_RING  0
#define SM_H0    98304
#define SM_H1    115200
#define SM_XB    132096
#define SM_WPS   134144
#define SM_ZB    150528
#define SM_TOTAL 154624

__device__ __forceinline__ float sigf(float x) { return 1.0f / (1.0f + __expf(-x)); }
__device__ __forceinline__ float tanhfast(float x) { return 1.0f - 2.0f / (__expf(2.0f * x) + 1.0f); }

__device__ __forceinline__ void stage16(const char* g, const char* l) {
    __builtin_amdgcn_global_load_lds((glob_uint*)g, (lds_uint*)l, 16, 0, 0);
}

#define BARRIER_LK do { \
    asm volatile("s_waitcnt lgkmcnt(0)" ::: "memory"); \
    __builtin_amdgcn_s_barrier(); \
    asm volatile("" ::: "memory"); \
    __builtin_amdgcn_sched_barrier(0); \
} while (0)

// ================= QUAD PATH (256 blocks x 256 threads, 4-way gate split) =================
// stream element: g*204800 + u*8192 + w*2048 + q*512 + e2
// panels u: 0..7 W0h kt=u | 8 W0x (register-resident, never staged) | 9..16 W1h | 17..24 W1x
// tile NT = q*16 + g*4 + w
__global__ void prep_quad(const float* __restrict__ wih0, const float* __restrict__ whh0,
                          const float* __restrict__ wih1, const float* __restrict__ whh1,
                          const float* __restrict__ wproj,
                          const float* __restrict__ bih0, const float* __restrict__ bhh0,
                          const float* __restrict__ bih1, const float* __restrict__ bhh1,
                          char* __restrict__ ws) {
    int idx = blockIdx.x * 256 + threadIdx.x;
    if (idx < 819200) {
        int g  = idx / 204800;
        int r  = idx - g * 204800;
        int u  = r >> 13;
        int r2 = r & 8191;
        int w  = r2 >> 11;
        int r3 = r2 & 2047;
        int q  = r3 >> 9;
        int e2 = r3 & 511;
        const float* src; int K, kt;
        if (u < 8)       { src = whh0; K = 256; kt = u; }
        else if (u == 8) { src = wih0; K = 20;  kt = 0; }
        else if (u < 17) { src = whh1; K = 256; kt = u - 9; }
        else             { src = wih1; K = 256; kt = u - 17; }
        int NT = q * 16 + g * 4 + w;
        int j = e2 & 7, lane = e2 >> 3;
        int n = NT * 16 + (lane & 15);
        int k = kt * 32 + ((lane >> 4) << 3) + j;
        float v = (k < K) ? src[n * K + k] : 0.0f;
        ((__hip_bfloat16*)(ws + OFF_WSTR))[idx] = __float2bfloat16(v);
    } else if (idx < 827392) {
        int e = idx - 819200;
        int j = e & 7, lane = (e >> 3) & 63, tile = e >> 9;
        int kt = tile & 7, nt = tile >> 3;
        int n = nt * 16 + (lane & 15);
        int k = kt * 32 + ((lane >> 4) << 3) + j;
        float v = (n < 20) ? wproj[n * 256 + k] : 0.0f;
        ((__hip_bfloat16*)(ws + OFF_WPROJ))[e] = __float2bfloat16(v);
    } else if (idx < 828416) {
        int j = idx - 827392; ((float*)(ws + OFF_B0))[j] = bih0[j] + bhh0[j];
    } else if (idx < 829440) {
        int j = idx - 828416; ((float*)(ws + OFF_B1))[j] = bih1[j] + bhh1[j];
    } else if (idx < 829952) {
        ((unsigned int*)(ws + OFF_FLAG))[idx - 829440] = 0;
    }
}

// grp = blockIdx&63, g = blockIdx>>6.
// Round-9 sync structure EXACTLY (tid<3 relay exchFinish, 2 barriers) +
// W0x register-resident (pure dataflow) + row-split phaseC stores.
__global__ __launch_bounds__(256, 1) void decoder_quad(
    const float* __restrict__ z, const float* __restrict__ w_lh, const float* __restrict__ b_lh,
    const float* __restrict__ w_lc, const float* __restrict__ b_lc,
    const float* __restrict__ b_proj, char* __restrict__ ws,
    float* __restrict__ out) {

    __shared__ __align__(16) char smem[QM_TOTAL];

    const int tid = threadIdx.x;
    const int grp = blockIdx.x & 63;
    const int g   = blockIdx.x >> 6;
    const int b0  = grp * NB;

    __hip_bfloat16* h0p = (__hip_bfloat16*)(smem + QM_H0);
    __hip_bfloat16* h1p = (__hip_bfloat16*)(smem + QM_H1);
    __hip_bfloat16* xbh = (__hip_bfloat16*)(smem + QM_XB);

    {
        float* zbf = (float*)(smem + QM_ZB);
        #pragma unroll
        for (int i = 0; i < 4; i++) {
            int ii = tid + i * 256;
            zbf[ii] = z[(b0 + (ii >> 5)) * 32 + (ii & 31)];
        }
        ((unsigned int*)(smem + QM_XB))[tid]       = 0;
        ((unsigned int*)(smem + QM_XB))[tid + 256] = 0;
        const bf16x8* sp = (const bf16x8*)(ws + OFF_WPROJ);
        bf16x8* dp = (bf16x8*)(smem + QM_WPS);
        #pragma unroll
        for (int i = 0; i < 4; i++) dp[tid + i * 256] = sp[tid + i * 256];
    }
    __syncthreads();

    {
        float* cinitf = (float*)(smem + QM_RING);   // overlay [2][32][256] f32
        const float* zbf = (const float*)(smem + QM_ZB);
        for (int ii = 0; ii < 64; ii++) {
            int pi = ii * 256 + tid;
            int b = pi >> 9, col = pi & 511;
            float dh = b_lh[col], dc = b_lc[col];
            #pragma unroll 8
            for (int k = 0; k < 32; k++) {
                float zv = zbf[b * 32 + k];
                dh += zv * w_lh[col * 32 + k];
                dc += zv * w_lc[col * 32 + k];
            }
            if (col < 256) { h0p[b * 264 + col]         = __float2bfloat16(dh); cinitf[b * 256 + col]                 = dc; }
            else           { h1p[b * 264 + (col - 256)] = __float2bfloat16(dh); cinitf[8192 + b * 256 + (col - 256)] = dc; }
        }
    }
    __syncthreads();

    const int w  = tid >> 6, ln = tid & 63;
    const int l15 = ln & 15, lq = ln >> 4;
    const int lnoff = ln * 16;
    const int colg = g * 64 + w * 16 + l15;

    float c0r[2][4], c1r[2][4];
    {
        const float* cinitf = (const float*)(smem + QM_RING);
        #pragma unroll
        for (int mt = 0; mt < 2; mt++)
            #pragma unroll
            for (int r = 0; r < 4; r++) {
                int m = mt * 16 + lq * 4 + r;
                c0r[mt][r] = cinitf[m * 256 + colg];
                c1r[mt][r] = cinitf[8192 + m * 256 + colg];
            }
    }
    __syncthreads();   // overlay dead; ring staging may start

    const float* bias0 = (const float*)(ws + OFF_B0);
    const float* bias1 = (const float*)(ws + OFF_B1);
    float bs0[4], bs1[4];
    #pragma unroll
    for (int q = 0; q < 4; q++) {
        bs0[q] = bias0[q * 256 + colg];
        bs1[q] = bias1[q * 256 + colg];
    }
    const int pc_nt = w & 1, pc_mt = w >> 1;
    const int pc_col = pc_nt * 16 + l15;
    const float bpj = (pc_col < 20) ? b_proj[pc_col] : 0.0f;

    const char* wps_c = smem + QM_WPS;
    const char* h0c = smem + QM_H0;
    const char* h1c = smem + QM_H1;
    const char* xbc = smem + QM_XB;
    float* outp = out;

    const char* wgl   = ws + OFF_WSTR + g * WQUARTER + w * 4096 + lnoff;
    char*       ringb = smem + QM_RING + w * 16384;           // 4 slots x 4KB
    const char* ringc = smem + QM_RING + w * 16384 + lnoff;
    int sOff = 0;
    int slS  = 0;
    int slR  = 0;

    // W0x register-resident (stream panel 8 = byte 131072, 16 VGPRs, loaded once)
    const bf16x8 wX0 = *(const bf16x8*)(wgl + 131072);
    const bf16x8 wX1 = *(const bf16x8*)(wgl + 131072 + 1024);
    const bf16x8 wX2 = *(const bf16x8*)(wgl + 131072 + 2048);
    const bf16x8 wX3 = *(const bf16x8*)(wgl + 131072 + 3072);

    f32x4 acc[4][2];
    bf16x8 wT0, wT1, wT2, wT3, afA, afB;

// stream skips panel 8 (131072 = 8*16384): 24 staged panels per step
#define STAGE_NEXT do { \
    stage16(wgl + sOff,        ringb + slS * 4096); \
    stage16(wgl + sOff + 1024, ringb + slS * 4096 + 1024); \
    stage16(wgl + sOff + 2048, ringb + slS * 4096 + 2048); \
    stage16(wgl + sOff + 3072, ringb + slS * 4096 + 3072); \
    sOff += 16384; \
    if (sOff == 131072) sOff += 16384; \
    if (sOff >= WQUARTER) sOff = 0; \
    slS = (slS + 1) & 3; \
} while (0)

// rule-#18 fence after counted waitcnt
#define WWAIT do { \
    asm volatile("s_waitcnt vmcnt(8)" ::: "memory"); \
    __builtin_amdgcn_sched_barrier(0); \
} while (0)

#define LOADW do { \
    const char* rb_ = ringc + slR * 4096; slR = (slR + 1) & 3; \
    wT0 = *(const bf16x8*)(rb_); \
    wT1 = *(const bf16x8*)(rb_ + 1024); \
    wT2 = *(const bf16x8*)(rb_ + 2048); \
    wT3 = *(const bf16x8*)(rb_ + 3072); \
} while (0)

#define LOADA(hsrc, ktv) do { \
    afA = *(const bf16x8*)((hsrc) + l15 * 528 + (ktv) * 64 + lq * 16); \
    afB = *(const bf16x8*)((hsrc) + (16 + l15) * 528 + (ktv) * 64 + lq * 16); \
} while (0)

#define LOADAX do { \
    afA = *(const bf16x8*)(xbc + l15 * 64 + lq * 16); \
    afB = *(const bf16x8*)(xbc + (16 + l15) * 64 + lq * 16); \
} while (0)

#define MFMA8 do { \
    acc[0][0] = __builtin_amdgcn_mfma_f32_16x16x32_bf16(afA, wT0, acc[0][0], 0, 0, 0); \
    acc[0][1] = __builtin_amdgcn_mfma_f32_16x16x32_bf16(afB, wT0, acc[0][1], 0, 0, 0); \
    acc[1][0] = __builtin_amdgcn_mfma_f32_16x16x32_bf16(afA, wT1, acc[1][0], 0, 0, 0); \
    acc[1][1] = __builtin_amdgcn_mfma_f32_16x16x32_bf16(afB, wT1, acc[1][1], 0, 0, 0); \
    acc[2][0] = __builtin_amdgcn_mfma_f32_16x16x32_bf16(afA, wT2, acc[2][0], 0, 0, 0); \
    acc[2][1] = __builtin_amdgcn_mfma_f32_16x16x32_bf16(afB, wT2, acc[2][1], 0, 0, 0); \
    acc[3][0] = __builtin_amdgcn_mfma_f32_16x16x32_bf16(afA, wT3, acc[3][0], 0, 0, 0); \
    acc[3][1] = __builtin_amdgcn_mfma_f32_16x16x32_bf16(afB, wT3, acc[3][1], 0, 0, 0); \
} while (0)

#define MFMA8X do { \
    acc[0][0] = __builtin_amdgcn_mfma_f32_16x16x32_bf16(afA, wX0, acc[0][0], 0, 0, 0); \
    acc[0][1] = __builtin_amdgcn_mfma_f32_16x16x32_bf16(afB, wX0, acc[0][1], 0, 0, 0); \
    acc[1][0] = __builtin_amdgcn_mfma_f32_16x16x32_bf16(afA, wX1, acc[1][0], 0, 0, 0); \
    acc[1][1] = __builtin_amdgcn_mfma_f32_16x16x32_bf16(afB, wX1, acc[1][1], 0, 0, 0); \
    acc[2][0] = __builtin_amdgcn_mfma_f32_16x16x32_bf16(afA, wX2, acc[2][0], 0, 0, 0); \
    acc[2][1] = __builtin_amdgcn_mfma_f32_16x16x32_bf16(afB, wX2, acc[2][1], 0, 0, 0); \
    acc[3][0] = __builtin_amdgcn_mfma_f32_16x16x32_bf16(afA, wX3, acc[3][0], 0, 0, 0); \
    acc[3][1] = __builtin_amdgcn_mfma_f32_16x16x32_bf16(afB, wX3, acc[3][1], 0, 0, 0); \
} while (0)

    // all 4 g-blocks compute identical py; each writes its own 8 output rows
    auto phaseC = [&](int t) {
        f32x4 py = {bpj, bpj, bpj, bpj};
        #pragma unroll
        for (int kt = 0; kt < 8; kt++) {
            bf16x8 ah = *(const bf16x8*)(h1c + (pc_mt * 16 + l15) * 528 + kt * 64 + lq * 16);
            bf16x8 wf = *(const bf16x8*)(wps_c + pc_nt * 8192 + kt * 1024 + lnoff);
            py = __builtin_amdgcn_mfma_f32_16x16x32_bf16(ah, wf, py, 0, 0, 0);
        }
        if (pc_col < 20) {
            #pragma unroll
            for (int r = 0; r < 4; r++) {
                int row = pc_mt * 16 + lq * 4 + r;
                if ((row >> 3) == g)
                    outp[((size_t)(b0 + row) * TT + (t - 1)) * DD + pc_col] = py[r];
                xbh[row * 32 + pc_col] = __float2bfloat16(py[r]);
            }
        }
    };

    unsigned int* exBase = (unsigned int*)(ws + OFF_EXCH);
    unsigned int* flBase = (unsigned int*)(ws + OFF_FLAG);

    auto exchStore = [&](int L, const char* hp, int t) {
        unsigned int* exO = exBase + ((grp * 2 + L) * 4 + g) * 1024;
        unsigned int* flO = flBase + (grp * 2 + L) * 4 + g;
        #pragma unroll
        for (int i = 0; i < 4; i++) {
            int wi = tid * 4 + i, m = wi >> 5, cp = wi & 31;
            unsigned int v = *(const unsigned int*)(hp + m * 528 + g * 128 + cp * 4);
            __hip_atomic_store(&exO[wi], v, __ATOMIC_RELAXED, __HIP_MEMORY_SCOPE_AGENT);
        }
        asm volatile("s_waitcnt vmcnt(0)" ::: "memory");
        if (tid == 0)
            __hip_atomic_store(flO, (unsigned int)(t + 1), __ATOMIC_RELAXED, __HIP_MEMORY_SCOPE_AGENT);
    };

    // round-9 proven structure: tid<3 relay spin, barrier, gather, barrier
    auto exchFinish = [&](int L, char* hp, unsigned int expect) {
        if (tid < 3) {
            int p = tid + (tid >= g);
            unsigned int* flP = flBase + (grp * 2 + L) * 4 + p;
            int spins = 0;
            while (__hip_atomic_load(flP, __ATOMIC_RELAXED, __HIP_MEMORY_SCOPE_AGENT) < expect) {
                __builtin_amdgcn_s_sleep(8);
                if (++spins > (1 << 11)) break;   // desync -> fast wrong answer, not hang
            }
        }
        BARRIER_LK;
        #pragma unroll
        for (int pp = 0; pp < 3; pp++) {
            int p = pp + (pp >= g);
            unsigned int* exP = exBase + ((grp * 2 + L) * 4 + p) * 1024;
            unsigned int pv[4];
            #pragma unroll
            for (int i = 0; i < 4; i++)
                pv[i] = __hip_atomic_load(&exP[tid * 4 + i], __ATOMIC_RELAXED, __HIP_MEMORY_SCOPE_AGENT);
            #pragma unroll
            for (int i = 0; i < 4; i++) {
                int wi = tid * 4 + i, m = wi >> 5, cp = wi & 31;
                *(unsigned int*)(hp + m * 528 + p * 128 + cp * 4) = pv[i];
            }
        }
        BARRIER_LK;
    };

    // ---- prologue: stage panels 0,1,2; preload wT(p0), af(kt0 of h0) ----
    STAGE_NEXT;          // u0 -> slot 0
    STAGE_NEXT;          // u1 -> slot 1
    STAGE_NEXT;          // u2 -> slot 2
    WWAIT;               // 4 wX + 12 stage loads in flight -> oldest 8 retired -> u0 landed
    LOADW;               // wT <- u0
    LOADA(h0c, 0);

    #pragma unroll 1
    for (int t = 0; t < TT; t++) {
        // ======== phase A: gates0 = bias0 + h0 @ W0h^T + x @ W0x^T ========
        #pragma unroll
        for (int q = 0; q < 4; q++) {
            f32x4 v = {bs0[q], bs0[q], bs0[q], bs0[q]};
            acc[q][0] = v; acc[q][1] = v;
        }
        // panels u0..u6 (W0h kt 0..6); prefetch af kt+1
        #pragma unroll 1
        for (int kt = 0; kt < 7; kt++) {
            STAGE_NEXT; MFMA8; WWAIT; LOADW; LOADA(h0c, kt + 1);
        }
        if (t > 0) {
            exchFinish(1, (char*)(smem + QM_H1), (unsigned int)t);  // h1(t-1) partners
            phaseC(t);                                               // y(t-1), xb(t)
        }
        BARRIER_LK;                       // xbh published
        STAGE_NEXT; MFMA8; WWAIT; LOADW; LOADAX;  // panel u7 (af=h0 kt7); wT <- u9; af <- xb
        MFMA8X;                                   // x @ W0x from resident regs
        LOADA(h1c, 0);                            // af for u9 (W1h kt0)
        BARRIER_LK;                       // pre-EW-A

        #pragma unroll
        for (int mt = 0; mt < 2; mt++)
            #pragma unroll
            for (int r = 0; r < 4; r++) {
                float iv = acc[0][mt][r], fv = acc[1][mt][r];
                float gv = acc[2][mt][r], ov = acc[3][mt][r];
                float cn = sigf(fv) * c0r[mt][r] + sigf(iv) * tanhfast(gv);
                float hn = sigf(ov) * tanhfast(cn);
                c0r[mt][r] = cn;
                h0p[(mt * 16 + lq * 4 + r) * 264 + colg] = __float2bfloat16(hn);
            }
        BARRIER_LK;                       // own h0 slice visible
        exchStore(0, h0c, t);             // post h0(t); finish deferred past W1h

        // ======== phase B: gates1 = bias1 + h1 @ W1h^T + h0_new @ W1x^T ========
        #pragma unroll
        for (int q = 0; q < 4; q++) {
            f32x4 v = {bs1[q], bs1[q], bs1[q], bs1[q]};
            acc[q][0] = v; acc[q][1] = v;
        }
        // panels u9..u15 (W1h kt 0..6); prefetch af kt+1
        #pragma unroll 1
        for (int kt = 0; kt < 7; kt++) {
            STAGE_NEXT; MFMA8; WWAIT; LOADW; LOADA(h1c, kt + 1);
        }
        STAGE_NEXT; MFMA8; WWAIT; LOADW;  // panel u16 (af=h1 kt7); NO af prefetch (h0 pending)
        exchFinish(0, (char*)(smem + QM_H0), (unsigned int)(t + 1));  // h0(t) partners land
        LOADA(h0c, 0);                    // af for u17 (now safe)
        // panels u17..u23 (W1x kt 0..6); prefetch af kt+1
        #pragma unroll 1
        for (int kt = 0; kt < 7; kt++) {
            STAGE_NEXT; MFMA8; WWAIT; LOADW; LOADA(h0c, kt + 1);
        }
        STAGE_NEXT; MFMA8; WWAIT; LOADW; LOADA(h0c, 0);   // panel u24; af for next step
        BARRIER_LK;                       // pre-EW-B

        #pragma unroll
        for (int mt = 0; mt < 2; mt++)
            #pragma unroll
            for (int r = 0; r < 4; r++) {
                float iv = acc[0][mt][r], fv = acc[1][mt][r];
                float gv = acc[2][mt][r], ov = acc[3][mt][r];
                float cn = sigf(fv) * c1r[mt][r] + sigf(iv) * tanhfast(gv);
                float hn = sigf(ov) * tanhfast(cn);
                c1r[mt][r] = cn;
                h1p[(mt * 16 + lq * 4 + r) * 264 + colg] = __float2bfloat16(hn);
            }
        BARRIER_LK;                       // own h1 slice visible
        exchStore(1, h1c, t);             // post h1(t)
    }

    exchFinish(1, (char*)(smem + QM_H1), (unsigned int)TT);
    phaseC(TT);

#undef STAGE_NEXT
#undef WWAIT
#undef LOADW
#undef LOADA
#undef LOADAX
#undef MFMA8
#undef MFMA8X
}

// ================= SOLO FALLBACK (round-3 proven kernel, 64 blocks) =================

__global__ void prep_solo(const float* __restrict__ wih0, const float* __restrict__ whh0,
                          const float* __restrict__ wih1, const float* __restrict__ whh1,
                          const float* __restrict__ wproj,
                          const float* __restrict__ bih0, const float* __restrict__ bhh0,
                          const float* __restrict__ bih1, const float* __restrict__ bhh1,
                          char* __restrict__ ws) {
    int idx = blockIdx.x * 256 + threadIdx.x;
    if (idx < 819200) {
        int s  = idx >> 12;
        int wv = (idx >> 9) & 7;
        int e2 = idx & 511;
        int u = s >> 2, qq = s & 3, half = u & 1;
        const float* src; int K, kt;
        if (u < 16)      { src = whh0; K = 256; kt = u >> 1; }
        else if (u < 18) { src = wih0; K = 20;  kt = 0; }
        else if (u < 34) { src = wih1; K = 256; kt = (u - 18) >> 1; }
        else             { src = whh1; K = 256; kt = (u - 34) >> 1; }
        int NT = half * 32 + (qq >> 1) * 16 + wv * 2 + (qq & 1);
        int j = e2 & 7, lane = e2 >> 3;
        int n = NT * 16 + (lane & 15);
        int k = kt * 32 + ((lane >> 4) << 3) + j;
        float v = (k < K) ? src[n * K + k] : 0.0f;
        ((__hip_bfloat16*)(ws + OFF_WSTR))[idx] = __float2bfloat16(v);
    } else if (idx < 827392) {
        int e = idx - 819200;
        int j = e & 7, lane = (e >> 3) & 63, tile = e >> 9;
        int kt = tile & 7, nt = tile >> 3;
        int n = nt * 16 + (lane & 15);
        int k = kt * 32 + ((lane >> 4) << 3) + j;
        float v = (n < 20) ? wproj[n * 256 + k] : 0.0f;
        ((__hip_bfloat16*)(ws + OFF_WPROJ))[e] = __float2bfloat16(v);
    } else if (idx < 828416) {
        int j = idx - 827392; ((float*)(ws + OFF_B0))[j] = bih0[j] + bhh0[j];
    } else if (idx < 829440) {
        int j = idx - 828416; ((float*)(ws + OFF_B1))[j] = bih1[j] + bhh1[j];
    }
}

__global__ __launch_bounds__(512, 1) void decoder_solo(
    const float* __restrict__ z, const float* __restrict__ w_lh, const float* __restrict__ b_lh,
    const float* __restrict__ w_lc, const float* __restrict__ b_lc,
    const float* __restrict__ b_proj, const char* __restrict__ ws,
    float* __restrict__ out) {

    __shared__ __align__(16) char smem[SM_TOTAL];

    const int tid = threadIdx.x;
    const int b0  = blockIdx.x * NB;

    __hip_bfloat16* h0p = (__hip_bfloat16*)(smem + SM_H0);
    __hip_bfloat16* h1p = (__hip_bfloat16*)(smem + SM_H1);
    __hip_bfloat16* xbh = (__hip_bfloat16*)(smem + SM_XB);

    {
        float* zbf = (float*)(smem + SM_ZB);
        zbf[tid]       = z[(b0 + (tid >> 5)) * 32 + (tid & 31)];
        int i2 = tid + 512;
        zbf[i2]        = z[(b0 + (i2 >> 5)) * 32 + (i2 & 31)];
        ((unsigned int*)(smem + SM_XB))[tid] = 0;
        const bf16x8* sp = (const bf16x8*)(ws + OFF_WPROJ);
        bf16x8* dp = (bf16x8*)(smem + SM_WPS);
        dp[tid] = sp[tid];
        dp[tid + 512] = sp[tid + 512];
    }
    __syncthreads();

    {
        float* cinitf = (float*)smem;
        const float* zbf = (const float*)(smem + SM_ZB);
        for (int ii = 0; ii < 32; ii++) {
            int pi = ii * 512 + tid;
            int b = pi >> 9, col = pi & 511;
            float dh = b_lh[col], dc = b_lc[col];
            #pragma unroll 8
            for (int k = 0; k < 32; k++) {
                float zv = zbf[b * 32 + k];
                dh += zv * w_lh[col * 32 + k];
                dc += zv * w_lc[col * 32 + k];
            }
            if (col < 256) { h0p[b * 264 + col]         = __float2bfloat16(dh); cinitf[b * 256 + col]                 = dc; }
            else           { h1p[b * 264 + (col - 256)] = __float2bfloat16(dh); cinitf[8192 + b * 256 + (col - 256)] = dc; }
        }
    }
    __syncthreads();

    const int wv = tid >> 6, ln = tid & 63;
    const int l15 = ln & 15, lq = ln >> 4;
    const int lnoff = ln * 16;

    float c0r[2][2][4], c1r[2][2][4];
    {
        const float* cinitf = (const float*)smem;
        #pragma unroll
        for (int mt = 0; mt < 2; mt++)
            #pragma unroll
            for (int h = 0; h < 2; h++)
                #pragma unroll
                for (int r = 0; r < 4; r++) {
                    int m = mt * 16 + lq * 4 + r, u = wv * 32 + h * 16 + l15;
                    c0r[mt][h][r] = cinitf[m * 256 + u];
                    c1r[mt][h][r] = cinitf[8192 + m * 256 + u];
                }
    }
    __syncthreads();

    const float* bias0 = (const float*)(ws + OFF_B0);
    const float* bias1 = (const float*)(ws + OFF_B1);
    float bs0[8], bs1[8];
    #pragma unroll
    for (int q = 0; q < 8; q++) {
        int col = (q >> 1) * 256 + wv * 32 + (q & 1) * 16 + l15;
        bs0[q] = bias0[col];
        bs1[q] = bias1[col];
    }
    const int pc_nt = wv & 1, pc_mt = wv >> 1;
    const int pc_col = pc_nt * 16 + l15;
    const float bpj = (wv < 4 && pc_col < 20) ? b_proj[pc_col] : 0.0f;

    const char* wps_c = smem + SM_WPS;
    const char* h0c = smem + SM_H0;
    const char* h1c = smem + SM_H1;
    const char* xbc = smem + SM_XB;

    float* outp = out;

    const char* wgl   = ws + OFF_WSTR + wv * 1024 + lnoff;
    char*       ringb = smem + SM_RING + wv * 12288;
    const char* ringc = smem + SM_RING + wv * 12288 + lnoff;
    int sOff = 2 * 32768;
    int slS  = 2;
    int slR  = 0;

    f32x4 acc[8][2];

    auto doPanel = [&](const char* hsrc, int kt, bool isX, int qbase) {
        bf16x8 af0, af1;
        if (isX) {
            af0 = *(const bf16x8*)(xbc + l15 * 64 + lq * 16);
            af1 = *(const bf16x8*)(xbc + (16 + l15) * 64 + lq * 16);
        } else {
            af0 = *(const bf16x8*)(hsrc + l15 * 528 + kt * 64 + lq * 16);
            af1 = *(const bf16x8*)(hsrc + (16 + l15) * 528 + kt * 64 + lq * 16);
        }
        #pragma unroll
        for (int j = 0; j < 4; j++)
            stage16(wgl + (sOff + j * 8192), ringb + slS * 4096 + j * 1024);
        sOff += 32768; if (sOff >= WSTR_BYTES) sOff = 0;
        slS = (slS == 2) ? 0 : slS + 1;
        asm volatile("s_waitcnt vmcnt(8)" ::: "memory");
        __builtin_amdgcn_sched_barrier(0);
        const char* rb = ringc + slR * 4096;
        slR = (slR == 2) ? 0 : slR + 1;
        bf16x8 w0 = *(const bf16x8*)(rb);
        bf16x8 w1 = *(const bf16x8*)(rb + 1024);
        bf16x8 w2 = *(const bf16x8*)(rb + 2048);
        bf16x8 w3 = *(const bf16x8*)(rb + 3072);
        acc[qbase + 0][0] = __builtin_amdgcn_mfma_f32_16x16x32_bf16(af0, w0, acc[qbase + 0][0], 0, 0, 0);
        acc[qbase + 0][1] = __builtin_amdgcn_mfma_f32_16x16x32_bf16(af1, w0, acc[qbase + 0][1], 0, 0, 0);
        acc[qbase + 1][0] = __builtin_amdgcn_mfma_f32_16x16x32_bf16(af0, w1, acc[qbase + 1][0], 0, 0, 0);
        acc[qbase + 1][1] = __builtin_amdgcn_mfma_f32_16x16x32_bf16(af1, w1, acc[qbase + 1][1], 0, 0, 0);
        acc[qbase + 2][0] = __builtin_amdgcn_mfma_f32_16x16x32_bf16(af0, w2, acc[qbase + 2][0], 0, 0, 0);
        acc[qbase + 2][1] = __builtin_amdgcn_mfma_f32_16x16x32_bf16(af1, w2, acc[qbase + 2][1], 0, 0, 0);
        acc[qbase + 3][0] = __builtin_amdgcn_mfma_f32_16x16x32_bf16(af0, w3, acc[qbase + 3][0], 0, 0, 0);
        acc[qbase + 3][1] = __builtin_amdgcn_mfma_f32_16x16x32_bf16(af1, w3, acc[qbase + 3][1], 0, 0, 0);
    };

    auto phaseC = [&](int t) {
        f32x4 py = {bpj, bpj, bpj, bpj};
        #pragma unroll
        for (int kt = 0; kt < 8; kt++) {
            bf16x8 ah = *(const bf16x8*)(h1c + (pc_mt * 16 + l15) * 528 + kt * 64 + lq * 16);
            bf16x8 wf = *(const bf16x8*)(wps_c + pc_nt * 8192 + kt * 1024 + lnoff);
            py = __builtin_amdgcn_mfma_f32_16x16x32_bf16(ah, wf, py, 0, 0, 0);
        }
        if (pc_col < 20) {
            #pragma unroll
            for (int r = 0; r < 4; r++) {
                int row = pc_mt * 16 + lq * 4 + r;
                outp[((size_t)(b0 + row) * TT + (t - 1)) * DD + pc_col] = py[r];
                xbh[row * 32 + pc_col] = __float2bfloat16(py[r]);
            }
        }
    };

    #pragma unroll
    for (int j = 0; j < 4; j++) stage16(wgl + j * 8192,         ringb + j * 1024);
    #pragma unroll
    for (int j = 0; j < 4; j++) stage16(wgl + 32768 + j * 8192, ringb + 4096 + j * 1024);

    #pragma unroll 1
    for (int t = 0; t < TT; t++) {
        #pragma unroll
        for (int q = 0; q < 8; q++) {
            f32x4 v = {bs0[q], bs0[q], bs0[q], bs0[q]};
            acc[q][0] = v; acc[q][1] = v;
        }
        if (t > 0 && wv < 4) phaseC(t);
        #pragma unroll 1
        for (int uu = 0; uu < 7; uu++) {
            doPanel(h0c, uu, false, 0);
            doPanel(h0c, uu, false, 4);
        }
        BARRIER_LK;
        doPanel(h0c, 7, false, 0);
        doPanel(h0c, 7, false, 4);
        doPanel(xbc, 0, true,  0);
        doPanel(xbc, 0, true,  4);
        BARRIER_LK;

        #pragma unroll
        for (int mt = 0; mt < 2; mt++)
            #pragma unroll
            for (int h = 0; h < 2; h++)
                #pragma unroll
                for (int r = 0; r < 4; r++) {
                    float iv = acc[0 + h][mt][r], fv = acc[2 + h][mt][r];
                    float gv = acc[4 + h][mt][r], ov = acc[6 + h][mt][r];
                    float cn = sigf(fv) * c0r[mt][h][r] + sigf(iv) * tanhfast(gv);
                    float hn = sigf(ov) * tanhfast(cn);
                    c0r[mt][h][r] = cn;
                    h0p[(mt * 16 + lq * 4 + r) * 264 + wv * 32 + h * 16 + l15] = __float2bfloat16(hn);
                }
        BARRIER_LK;

        #pragma unroll
        for (int q = 0; q < 8; q++) {
            f32x4 v = {bs1[q], bs1[q], bs1[q], bs1[q]};
            acc[q][0] = v; acc[q][1] = v;
        }
        #pragma unroll 1
        for (int uu = 0; uu < 8; uu++) {
            doPanel(h0c, uu, false, 0);
            doPanel(h0c, uu, false, 4);
        }
        #pragma unroll 1
        for (int uu = 0; uu < 8; uu++) {
            doPanel(h1c, uu, false, 0);
            doPanel(h1c, uu, false, 4);
        }
        BARRIER_LK;

        #pragma unroll
        for (int mt = 0; mt < 2; mt++)
            #pragma unroll
            for (int h = 0; h < 2; h++)
                #pragma unroll
                for (int r = 0; r < 4; r++) {
                    float iv = acc[0 + h][mt][r], fv = acc[2 + h][mt][r];
                    float gv = acc[4 + h][mt][r], ov = acc[6 + h][mt][r];
                    float cn = sigf(fv) * c1r[mt][h][r] + sigf(iv) * tanhfast(gv);
                    float hn = sigf(ov) * tanhfast(cn);
                    c1r[mt][h][r] = cn;
                    h1p[(mt * 16 + lq * 4 + r) * 264 + wv * 32 + h * 16 + l15] = __float2bfloat16(hn);
                }
        BARRIER_LK;
    }

    if (wv < 4) phaseC(TT);
}

// ================= launcher =================

extern "C" void kernel_launch(void* const* d_in, const int* in_sizes, int n_in,
                              void* d_out, int out_size, void* d_ws, size_t ws_size,
                              hipStream_t stream) {
    const float* z      = (const float*)d_in[0];
    const float* w_lh   = (const float*)d_in[3];
    const float* b_lh   = (const float*)d_in[4];
    const float* w_lc   = (const float*)d_in[5];
    const float* b_lc   = (const float*)d_in[6];
    const float* w_ih0  = (const float*)d_in[7];
    const float* w_hh0  = (const float*)d_in[8];
    const float* b_ih0  = (const float*)d_in[9];
    const float* b_hh0  = (const float*)d_in[10];
    const float* w_ih1  = (const float*)d_in[11];
    const float* w_hh1  = (const float*)d_in[12];
    const float* b_ih1  = (const float*)d_in[13];
    const float* b_hh1  = (const float*)d_in[14];
    const float* w_proj = (const float*)d_in[15];
    const float* b_proj = (const float*)d_in[16];
    char* ws = (char*)d_ws;
    float* out = (float*)d_out;

    if (ws_size >= (size_t)WS_NEED_QUAD) {
        prep_quad<<<3242, 256, 0, stream>>>(w_ih0, w_hh0, w_ih1, w_hh1, w_proj,
                                            b_ih0, b_hh0, b_ih1, b_hh1, ws);
        decoder_quad<<<256, 256, 0, stream>>>(z, w_lh, b_lh, w_lc, b_lc, b_proj, ws, out);
    } else {
        prep_solo<<<3240, 256, 0, stream>>>(w_ih0, w_hh0, w_ih1, w_hh1, w_proj,
                                            b_ih0, b_hh0, b_ih1, b_hh1, ws);
        decoder_solo<<<64, 512, 0, stream>>>(z, w_lh, b_lh, w_lc, b_lc, b_proj, ws, out);
    }
}

// Round 13
// 5758.839 us; speedup vs baseline: 1.9672x; 1.0716x over previous
//
#include <hip/hip_runtime.h>
#include <hip/hip_bf16.h>

#define NB 32
#define TT 512
#define DD 20

using bf16x8 = __attribute__((ext_vector_type(8))) short;
using f32x4  = __attribute__((ext_vector_type(4))) float;

typedef __attribute__((address_space(3))) unsigned int lds_uint;
typedef __attribute__((address_space(1))) unsigned int glob_uint;

// ---- workspace offsets ----
#define OFF_WSTR  0          // 1,638,400 B weight stream (layout differs quad vs solo)
#define OFF_WPROJ 1638400
#define OFF_B0    1654784
#define OFF_B1    1658880
#define OFF_EXCH  1662976    // quad: 64 grps x 2 layers x 4 g x 4KB = 2MB
#define OFF_FLAG  3760128    // quad: 512 u32
#define WS_NEED_QUAD 3762176
#define WQUARTER  409600     // 25 panels x 4 waves x 4KB
#define WSTR_BYTES 1638400

// ---- quad smem layout: ring depth 4 (16KB/wave x 4 waves = 64KB) ----
#define QM_H0    0        // 32*264*2 = 16896
#define QM_H1    16896
#define QM_XB    33792    // 2048
#define QM_WPS   35840    // 16384
#define QM_ZB    52224    // 4096
#define QM_RING  56320    // 4 waves x 4 slots x 4KB = 65536 (cinit 64K overlay here)
#define QM_TOTAL 121856

// ---- solo smem layout (round-3 proven) ----
#define SM_RING  0
#define SM_H0    98304
#define SM_H1    115200
#define SM_XB    132096
#define SM_WPS   134144
#define SM_ZB    150528
#define SM_TOTAL 154624

__device__ __forceinline__ float sigf(float x) { return 1.0f / (1.0f + __expf(-x)); }
__device__ __forceinline__ float tanhfast(float x) { return 1.0f - 2.0f / (__expf(2.0f * x) + 1.0f); }

__device__ __forceinline__ void stage16(const char* g, const char* l) {
    __builtin_amdgcn_global_load_lds((glob_uint*)g, (lds_uint*)l, 16, 0, 0);
}

#define BARRIER_LK do { \
    asm volatile("s_waitcnt lgkmcnt(0)" ::: "memory"); \
    __builtin_amdgcn_s_barrier(); \
    asm volatile("" ::: "memory"); \
    __builtin_amdgcn_sched_barrier(0); \
} while (0)

// ================= QUAD PATH (256 blocks x 256 threads, 4-way gate split) =================
// stream element: g*204800 + u*8192 + w*2048 + q*512 + e2
// panels u: 0..7 W0h kt=u | 8 W0x (register-resident, never staged) | 9..16 W1h | 17..24 W1x
// tile NT = q*16 + g*4 + w
__global__ void prep_quad(const float* __restrict__ wih0, const float* __restrict__ whh0,
                          const float* __restrict__ wih1, const float* __restrict__ whh1,
                          const float* __restrict__ wproj,
                          const float* __restrict__ bih0, const float* __restrict__ bhh0,
                          const float* __restrict__ bih1, const float* __restrict__ bhh1,
                          char* __restrict__ ws) {
    int idx = blockIdx.x * 256 + threadIdx.x;
    if (idx < 819200) {
        int g  = idx / 204800;
        int r  = idx - g * 204800;
        int u  = r >> 13;
        int r2 = r & 8191;
        int w  = r2 >> 11;
        int r3 = r2 & 2047;
        int q  = r3 >> 9;
        int e2 = r3 & 511;
        const float* src; int K, kt;
        if (u < 8)       { src = whh0; K = 256; kt = u; }
        else if (u == 8) { src = wih0; K = 20;  kt = 0; }
        else if (u < 17) { src = whh1; K = 256; kt = u - 9; }
        else             { src = wih1; K = 256; kt = u - 17; }
        int NT = q * 16 + g * 4 + w;
        int j = e2 & 7, lane = e2 >> 3;
        int n = NT * 16 + (lane & 15);
        int k = kt * 32 + ((lane >> 4) << 3) + j;
        float v = (k < K) ? src[n * K + k] : 0.0f;
        ((__hip_bfloat16*)(ws + OFF_WSTR))[idx] = __float2bfloat16(v);
    } else if (idx < 827392) {
        int e = idx - 819200;
        int j = e & 7, lane = (e >> 3) & 63, tile = e >> 9;
        int kt = tile & 7, nt = tile >> 3;
        int n = nt * 16 + (lane & 15);
        int k = kt * 32 + ((lane >> 4) << 3) + j;
        float v = (n < 20) ? wproj[n * 256 + k] : 0.0f;
        ((__hip_bfloat16*)(ws + OFF_WPROJ))[e] = __float2bfloat16(v);
    } else if (idx < 828416) {
        int j = idx - 827392; ((float*)(ws + OFF_B0))[j] = bih0[j] + bhh0[j];
    } else if (idx < 829440) {
        int j = idx - 828416; ((float*)(ws + OFF_B1))[j] = bih1[j] + bhh1[j];
    } else if (idx < 829952) {
        ((unsigned int*)(ws + OFF_FLAG))[idx - 829440] = 0;
    }
}

// grp = blockIdx&63, g = blockIdx>>6.
// Round-12 base + deferred-flag exchange (no vmcnt(0) drains in main loop) +
// batched exchFinish gather. Sync skeleton (tid<3 relay, 2 barriers) unchanged.
__global__ __launch_bounds__(256, 1) void decoder_quad(
    const float* __restrict__ z, const float* __restrict__ w_lh, const float* __restrict__ b_lh,
    const float* __restrict__ w_lc, const float* __restrict__ b_lc,
    const float* __restrict__ b_proj, char* __restrict__ ws,
    float* __restrict__ out) {

    __shared__ __align__(16) char smem[QM_TOTAL];

    const int tid = threadIdx.x;
    const int grp = blockIdx.x & 63;
    const int g   = blockIdx.x >> 6;
    const int b0  = grp * NB;

    __hip_bfloat16* h0p = (__hip_bfloat16*)(smem + QM_H0);
    __hip_bfloat16* h1p = (__hip_bfloat16*)(smem + QM_H1);
    __hip_bfloat16* xbh = (__hip_bfloat16*)(smem + QM_XB);

    {
        float* zbf = (float*)(smem + QM_ZB);
        #pragma unroll
        for (int i = 0; i < 4; i++) {
            int ii = tid + i * 256;
            zbf[ii] = z[(b0 + (ii >> 5)) * 32 + (ii & 31)];
        }
        ((unsigned int*)(smem + QM_XB))[tid]       = 0;
        ((unsigned int*)(smem + QM_XB))[tid + 256] = 0;
        const bf16x8* sp = (const bf16x8*)(ws + OFF_WPROJ);
        bf16x8* dp = (bf16x8*)(smem + QM_WPS);
        #pragma unroll
        for (int i = 0; i < 4; i++) dp[tid + i * 256] = sp[tid + i * 256];
    }
    __syncthreads();

    {
        float* cinitf = (float*)(smem + QM_RING);   // overlay [2][32][256] f32
        const float* zbf = (const float*)(smem + QM_ZB);
        for (int ii = 0; ii < 64; ii++) {
            int pi = ii * 256 + tid;
            int b = pi >> 9, col = pi & 511;
            float dh = b_lh[col], dc = b_lc[col];
            #pragma unroll 8
            for (int k = 0; k < 32; k++) {
                float zv = zbf[b * 32 + k];
                dh += zv * w_lh[col * 32 + k];
                dc += zv * w_lc[col * 32 + k];
            }
            if (col < 256) { h0p[b * 264 + col]         = __float2bfloat16(dh); cinitf[b * 256 + col]                 = dc; }
            else           { h1p[b * 264 + (col - 256)] = __float2bfloat16(dh); cinitf[8192 + b * 256 + (col - 256)] = dc; }
        }
    }
    __syncthreads();

    const int w  = tid >> 6, ln = tid & 63;
    const int l15 = ln & 15, lq = ln >> 4;
    const int lnoff = ln * 16;
    const int colg = g * 64 + w * 16 + l15;

    float c0r[2][4], c1r[2][4];
    {
        const float* cinitf = (const float*)(smem + QM_RING);
        #pragma unroll
        for (int mt = 0; mt < 2; mt++)
            #pragma unroll
            for (int r = 0; r < 4; r++) {
                int m = mt * 16 + lq * 4 + r;
                c0r[mt][r] = cinitf[m * 256 + colg];
                c1r[mt][r] = cinitf[8192 + m * 256 + colg];
            }
    }
    __syncthreads();   // overlay dead; ring staging may start

    const float* bias0 = (const float*)(ws + OFF_B0);
    const float* bias1 = (const float*)(ws + OFF_B1);
    float bs0[4], bs1[4];
    #pragma unroll
    for (int q = 0; q < 4; q++) {
        bs0[q] = bias0[q * 256 + colg];
        bs1[q] = bias1[q * 256 + colg];
    }
    const int pc_nt = w & 1, pc_mt = w >> 1;
    const int pc_col = pc_nt * 16 + l15;
    const float bpj = (pc_col < 20) ? b_proj[pc_col] : 0.0f;

    const char* wps_c = smem + QM_WPS;
    const char* h0c = smem + QM_H0;
    const char* h1c = smem + QM_H1;
    const char* xbc = smem + QM_XB;
    float* outp = out;

    const char* wgl   = ws + OFF_WSTR + g * WQUARTER + w * 4096 + lnoff;
    char*       ringb = smem + QM_RING + w * 16384;           // 4 slots x 4KB
    const char* ringc = smem + QM_RING + w * 16384 + lnoff;
    int sOff = 0;
    int slS  = 0;
    int slR  = 0;

    // W0x register-resident (stream panel 8 = byte 131072, 16 VGPRs, loaded once)
    const bf16x8 wX0 = *(const bf16x8*)(wgl + 131072);
    const bf16x8 wX1 = *(const bf16x8*)(wgl + 131072 + 1024);
    const bf16x8 wX2 = *(const bf16x8*)(wgl + 131072 + 2048);
    const bf16x8 wX3 = *(const bf16x8*)(wgl + 131072 + 3072);

    f32x4 acc[4][2];
    bf16x8 wT0, wT1, wT2, wT3, afA, afB;

// stream skips panel 8 (131072 = 8*16384): 24 staged panels per step
#define STAGE_NEXT do { \
    stage16(wgl + sOff,        ringb + slS * 4096); \
    stage16(wgl + sOff + 1024, ringb + slS * 4096 + 1024); \
    stage16(wgl + sOff + 2048, ringb + slS * 4096 + 2048); \
    stage16(wgl + sOff + 3072, ringb + slS * 4096 + 3072); \
    sOff += 16384; \
    if (sOff == 131072) sOff += 16384; \
    if (sOff >= WQUARTER) sOff = 0; \
    slS = (slS + 1) & 3; \
} while (0)

// rule-#18 fence after counted waitcnt
#define WWAIT do { \
    asm volatile("s_waitcnt vmcnt(8)" ::: "memory"); \
    __builtin_amdgcn_sched_barrier(0); \
} while (0)

#define LOADW do { \
    const char* rb_ = ringc + slR * 4096; slR = (slR + 1) & 3; \
    wT0 = *(const bf16x8*)(rb_); \
    wT1 = *(const bf16x8*)(rb_ + 1024); \
    wT2 = *(const bf16x8*)(rb_ + 2048); \
    wT3 = *(const bf16x8*)(rb_ + 3072); \
} while (0)

#define LOADA(hsrc, ktv) do { \
    afA = *(const bf16x8*)((hsrc) + l15 * 528 + (ktv) * 64 + lq * 16); \
    afB = *(const bf16x8*)((hsrc) + (16 + l15) * 528 + (ktv) * 64 + lq * 16); \
} while (0)

#define LOADAX do { \
    afA = *(const bf16x8*)(xbc + l15 * 64 + lq * 16); \
    afB = *(const bf16x8*)(xbc + (16 + l15) * 64 + lq * 16); \
} while (0)

#define MFMA8 do { \
    acc[0][0] = __builtin_amdgcn_mfma_f32_16x16x32_bf16(afA, wT0, acc[0][0], 0, 0, 0); \
    acc[0][1] = __builtin_amdgcn_mfma_f32_16x16x32_bf16(afB, wT0, acc[0][1], 0, 0, 0); \
    acc[1][0] = __builtin_amdgcn_mfma_f32_16x16x32_bf16(afA, wT1, acc[1][0], 0, 0, 0); \
    acc[1][1] = __builtin_amdgcn_mfma_f32_16x16x32_bf16(afB, wT1, acc[1][1], 0, 0, 0); \
    acc[2][0] = __builtin_amdgcn_mfma_f32_16x16x32_bf16(afA, wT2, acc[2][0], 0, 0, 0); \
    acc[2][1] = __builtin_amdgcn_mfma_f32_16x16x32_bf16(afB, wT2, acc[2][1], 0, 0, 0); \
    acc[3][0] = __builtin_amdgcn_mfma_f32_16x16x32_bf16(afA, wT3, acc[3][0], 0, 0, 0); \
    acc[3][1] = __builtin_amdgcn_mfma_f32_16x16x32_bf16(afB, wT3, acc[3][1], 0, 0, 0); \
} while (0)

#define MFMA8X do { \
    acc[0][0] = __builtin_amdgcn_mfma_f32_16x16x32_bf16(afA, wX0, acc[0][0], 0, 0, 0); \
    acc[0][1] = __builtin_amdgcn_mfma_f32_16x16x32_bf16(afB, wX0, acc[0][1], 0, 0, 0); \
    acc[1][0] = __builtin_amdgcn_mfma_f32_16x16x32_bf16(afA, wX1, acc[1][0], 0, 0, 0); \
    acc[1][1] = __builtin_amdgcn_mfma_f32_16x16x32_bf16(afB, wX1, acc[1][1], 0, 0, 0); \
    acc[2][0] = __builtin_amdgcn_mfma_f32_16x16x32_bf16(afA, wX2, acc[2][0], 0, 0, 0); \
    acc[2][1] = __builtin_amdgcn_mfma_f32_16x16x32_bf16(afB, wX2, acc[2][1], 0, 0, 0); \
    acc[3][0] = __builtin_amdgcn_mfma_f32_16x16x32_bf16(afA, wX3, acc[3][0], 0, 0, 0); \
    acc[3][1] = __builtin_amdgcn_mfma_f32_16x16x32_bf16(afB, wX3, acc[3][1], 0, 0, 0); \
} while (0)

    // all 4 g-blocks compute identical py; each writes its own 8 output rows
    auto phaseC = [&](int t) {
        f32x4 py = {bpj, bpj, bpj, bpj};
        #pragma unroll
        for (int kt = 0; kt < 8; kt++) {
            bf16x8 ah = *(const bf16x8*)(h1c + (pc_mt * 16 + l15) * 528 + kt * 64 + lq * 16);
            bf16x8 wf = *(const bf16x8*)(wps_c + pc_nt * 8192 + kt * 1024 + lnoff);
            py = __builtin_amdgcn_mfma_f32_16x16x32_bf16(ah, wf, py, 0, 0, 0);
        }
        if (pc_col < 20) {
            #pragma unroll
            for (int r = 0; r < 4; r++) {
                int row = pc_mt * 16 + lq * 4 + r;
                if ((row >> 3) == g)
                    outp[((size_t)(b0 + row) * TT + (t - 1)) * DD + pc_col] = py[r];
                xbh[row * 32 + pc_col] = __float2bfloat16(py[r]);
            }
        }
    };

    unsigned int* exBase = (unsigned int*)(ws + OFF_EXCH);
    unsigned int* flBase = (unsigned int*)(ws + OFF_FLAG);
    unsigned int* flO0 = flBase + (grp * 2 + 0) * 4 + g;
    unsigned int* flO1 = flBase + (grp * 2 + 1) * 4 + g;

    // stores only — flag is posted 2 panels later (after 2nd WWAIT), where
    // vmcnt(8) proves the 4 stores retired without any vmcnt(0) drain.
    auto exchPost = [&](int L, const char* hp) {
        unsigned int* exO = exBase + ((grp * 2 + L) * 4 + g) * 1024;
        #pragma unroll
        for (int i = 0; i < 4; i++) {
            int wi = tid * 4 + i, m = wi >> 5, cp = wi & 31;
            unsigned int v = *(const unsigned int*)(hp + m * 528 + g * 128 + cp * 4);
            __hip_atomic_store(&exO[wi], v, __ATOMIC_RELAXED, __HIP_MEMORY_SCOPE_AGENT);
        }
    };

    // round-9 proven structure: tid<3 relay spin, barrier, batched gather, barrier
    auto exchFinish = [&](int L, char* hp, unsigned int expect) {
        if (tid < 3) {
            int p = tid + (tid >= g);
            unsigned int* flP = flBase + (grp * 2 + L) * 4 + p;
            int spins = 0;
            while (__hip_atomic_load(flP, __ATOMIC_RELAXED, __HIP_MEMORY_SCOPE_AGENT) < expect) {
                __builtin_amdgcn_s_sleep(8);
                if (++spins > (1 << 11)) break;   // desync -> fast wrong answer, not hang
            }
        }
        BARRIER_LK;
        unsigned int pv[12];
        #pragma unroll
        for (int pp = 0; pp < 3; pp++) {
            int p = pp + (pp >= g);
            unsigned int* exP = exBase + ((grp * 2 + L) * 4 + p) * 1024;
            #pragma unroll
            for (int i = 0; i < 4; i++)
                pv[pp * 4 + i] = __hip_atomic_load(&exP[tid * 4 + i], __ATOMIC_RELAXED, __HIP_MEMORY_SCOPE_AGENT);
        }
        #pragma unroll
        for (int pp = 0; pp < 3; pp++) {
            int p = pp + (pp >= g);
            #pragma unroll
            for (int i = 0; i < 4; i++) {
                int wi = tid * 4 + i, m = wi >> 5, cp = wi & 31;
                *(unsigned int*)(hp + m * 528 + p * 128 + cp * 4) = pv[pp * 4 + i];
            }
        }
        BARRIER_LK;
    };

    // ---- prologue: stage panels 0,1,2; preload wT(p0), af(kt0 of h0) ----
    STAGE_NEXT;          // u0 -> slot 0
    STAGE_NEXT;          // u1 -> slot 1
    STAGE_NEXT;          // u2 -> slot 2
    WWAIT;               // 4 wX + 12 stage loads in flight -> oldest 8 retired -> u0 landed
    LOADW;               // wT <- u0
    LOADA(h0c, 0);

    #pragma unroll 1
    for (int t = 0; t < TT; t++) {
        // ======== phase A: gates0 = bias0 + h0 @ W0h^T + x @ W0x^T ========
        #pragma unroll
        for (int q = 0; q < 4; q++) {
            f32x4 v = {bs0[q], bs0[q], bs0[q], bs0[q]};
            acc[q][0] = v; acc[q][1] = v;
        }
        // panels u0,u1 (W0h kt 0,1) then deferred flag1 = t (h1(t-1) stores retired)
        STAGE_NEXT; MFMA8; WWAIT; LOADW; LOADA(h0c, 1);
        STAGE_NEXT; MFMA8; WWAIT; LOADW; LOADA(h0c, 2);
        if (tid == 0)
            __hip_atomic_store(flO1, (unsigned int)t, __ATOMIC_RELAXED, __HIP_MEMORY_SCOPE_AGENT);
        // panels u2..u6 (W0h kt 2..6); prefetch af kt+1
        #pragma unroll 1
        for (int kt = 2; kt < 7; kt++) {
            STAGE_NEXT; MFMA8; WWAIT; LOADW; LOADA(h0c, kt + 1);
        }
        if (t > 0) {
            exchFinish(1, (char*)(smem + QM_H1), (unsigned int)t);  // h1(t-1) partners
            phaseC(t);                                               // y(t-1), xb(t)
        }
        BARRIER_LK;                       // xbh published
        STAGE_NEXT; MFMA8; WWAIT; LOADW; LOADAX;  // panel u7 (af=h0 kt7); wT <- u9; af <- xb
        MFMA8X;                                   // x @ W0x from resident regs
        LOADA(h1c, 0);                            // af for u9 (W1h kt0)
        BARRIER_LK;                       // pre-EW-A

        #pragma unroll
        for (int mt = 0; mt < 2; mt++)
            #pragma unroll
            for (int r = 0; r < 4; r++) {
                float iv = acc[0][mt][r], fv = acc[1][mt][r];
                float gv = acc[2][mt][r], ov = acc[3][mt][r];
                float cn = sigf(fv) * c0r[mt][r] + sigf(iv) * tanhfast(gv);
                float hn = sigf(ov) * tanhfast(cn);
                c0r[mt][r] = cn;
                h0p[(mt * 16 + lq * 4 + r) * 264 + colg] = __float2bfloat16(hn);
            }
        BARRIER_LK;                       // own h0 slice visible
        exchPost(0, h0c);                 // post h0(t); flag deferred into W1h

        // ======== phase B: gates1 = bias1 + h1 @ W1h^T + h0_new @ W1x^T ========
        #pragma unroll
        for (int q = 0; q < 4; q++) {
            f32x4 v = {bs1[q], bs1[q], bs1[q], bs1[q]};
            acc[q][0] = v; acc[q][1] = v;
        }
        // panels u9,u10 (W1h kt 0,1) then deferred flag0 = t+1 (h0(t) stores retired)
        STAGE_NEXT; MFMA8; WWAIT; LOADW; LOADA(h1c, 1);
        STAGE_NEXT; MFMA8; WWAIT; LOADW; LOADA(h1c, 2);
        if (tid == 0)
            __hip_atomic_store(flO0, (unsigned int)(t + 1), __ATOMIC_RELAXED, __HIP_MEMORY_SCOPE_AGENT);
        // panels u11..u15 (W1h kt 2..6); prefetch af kt+1
        #pragma unroll 1
        for (int kt = 2; kt < 7; kt++) {
            STAGE_NEXT; MFMA8; WWAIT; LOADW; LOADA(h1c, kt + 1);
        }
        STAGE_NEXT; MFMA8; WWAIT; LOADW;  // panel u16 (af=h1 kt7); NO af prefetch (h0 pending)
        exchFinish(0, (char*)(smem + QM_H0), (unsigned int)(t + 1));  // h0(t) partners land
        LOADA(h0c, 0);                    // af for u17 (now safe)
        // panels u17..u23 (W1x kt 0..6); prefetch af kt+1
        #pragma unroll 1
        for (int kt = 0; kt < 7; kt++) {
            STAGE_NEXT; MFMA8; WWAIT; LOADW; LOADA(h0c, kt + 1);
        }
        STAGE_NEXT; MFMA8; WWAIT; LOADW; LOADA(h0c, 0);   // panel u24; af for next step
        BARRIER_LK;                       // pre-EW-B

        #pragma unroll
        for (int mt = 0; mt < 2; mt++)
            #pragma unroll
            for (int r = 0; r < 4; r++) {
                float iv = acc[0][mt][r], fv = acc[1][mt][r];
                float gv = acc[2][mt][r], ov = acc[3][mt][r];
                float cn = sigf(fv) * c1r[mt][r] + sigf(iv) * tanhfast(gv);
                float hn = sigf(ov) * tanhfast(cn);
                c1r[mt][r] = cn;
                h1p[(mt * 16 + lq * 4 + r) * 264 + colg] = __float2bfloat16(hn);
            }
        BARRIER_LK;                       // own h1 slice visible
        exchPost(1, h1c);                 // post h1(t); flag deferred to next step's phase A
    }

    // epilogue: drain the final h1 stores, post flag TT, gather, final phaseC
    asm volatile("s_waitcnt vmcnt(0)" ::: "memory");
    if (tid == 0)
        __hip_atomic_store(flO1, (unsigned int)TT, __ATOMIC_RELAXED, __HIP_MEMORY_SCOPE_AGENT);
    exchFinish(1, (char*)(smem + QM_H1), (unsigned int)TT);
    phaseC(TT);

#undef STAGE_NEXT
#undef WWAIT
#undef LOADW
#undef LOADA
#undef LOADAX
#undef MFMA8
#undef MFMA8X
}

// ================= SOLO FALLBACK (round-3 proven kernel, 64 blocks) =================

__global__ void prep_solo(const float* __restrict__ wih0, const float* __restrict__ whh0,
                          const float* __restrict__ wih1, const float* __restrict__ whh1,
                          const float* __restrict__ wproj,
                          const float* __restrict__ bih0, const float* __restrict__ bhh0,
                          const float* __restrict__ bih1, const float* __restrict__ bhh1,
                          char* __restrict__ ws) {
    int idx = blockIdx.x * 256 + threadIdx.x;
    if (idx < 819200) {
        int s  = idx >> 12;
        int wv = (idx >> 9) & 7;
        int e2 = idx & 511;
        int u = s >> 2, qq = s & 3, half = u & 1;
        const float* src; int K, kt;
        if (u < 16)      { src = whh0; K = 256; kt = u >> 1; }
        else if (u < 18) { src = wih0; K = 20;  kt = 0; }
        else if (u < 34) { src = wih1; K = 256; kt = (u - 18) >> 1; }
        else             { src = whh1; K = 256; kt = (u - 34) >> 1; }
        int NT = half * 32 + (qq >> 1) * 16 + wv * 2 + (qq & 1);
        int j = e2 & 7, lane = e2 >> 3;
        int n = NT * 16 + (lane & 15);
        int k = kt * 32 + ((lane >> 4) << 3) + j;
        float v = (k < K) ? src[n * K + k] : 0.0f;
        ((__hip_bfloat16*)(ws + OFF_WSTR))[idx] = __float2bfloat16(v);
    } else if (idx < 827392) {
        int e = idx - 819200;
        int j = e & 7, lane = (e >> 3) & 63, tile = e >> 9;
        int kt = tile & 7, nt = tile >> 3;
        int n = nt * 16 + (lane & 15);
        int k = kt * 32 + ((lane >> 4) << 3) + j;
        float v = (n < 20) ? wproj[n * 256 + k] : 0.0f;
        ((__hip_bfloat16*)(ws + OFF_WPROJ))[e] = __float2bfloat16(v);
    } else if (idx < 828416) {
        int j = idx - 827392; ((float*)(ws + OFF_B0))[j] = bih0[j] + bhh0[j];
    } else if (idx < 829440) {
        int j = idx - 828416; ((float*)(ws + OFF_B1))[j] = bih1[j] + bhh1[j];
    }
}

__global__ __launch_bounds__(512, 1) void decoder_solo(
    const float* __restrict__ z, const float* __restrict__ w_lh, const float* __restrict__ b_lh,
    const float* __restrict__ w_lc, const float* __restrict__ b_lc,
    const float* __restrict__ b_proj, const char* __restrict__ ws,
    float* __restrict__ out) {

    __shared__ __align__(16) char smem[SM_TOTAL];

    const int tid = threadIdx.x;
    const int b0  = blockIdx.x * NB;

    __hip_bfloat16* h0p = (__hip_bfloat16*)(smem + SM_H0);
    __hip_bfloat16* h1p = (__hip_bfloat16*)(smem + SM_H1);
    __hip_bfloat16* xbh = (__hip_bfloat16*)(smem + SM_XB);

    {
        float* zbf = (float*)(smem + SM_ZB);
        zbf[tid]       = z[(b0 + (tid >> 5)) * 32 + (tid & 31)];
        int i2 = tid + 512;
        zbf[i2]        = z[(b0 + (i2 >> 5)) * 32 + (i2 & 31)];
        ((unsigned int*)(smem + SM_XB))[tid] = 0;
        const bf16x8* sp = (const bf16x8*)(ws + OFF_WPROJ);
        bf16x8* dp = (bf16x8*)(smem + SM_WPS);
        dp[tid] = sp[tid];
        dp[tid + 512] = sp[tid + 512];
    }
    __syncthreads();

    {
        float* cinitf = (float*)smem;
        const float* zbf = (const float*)(smem + SM_ZB);
        for (int ii = 0; ii < 32; ii++) {
            int pi = ii * 512 + tid;
            int b = pi >> 9, col = pi & 511;
            float dh = b_lh[col], dc = b_lc[col];
            #pragma unroll 8
            for (int k = 0; k < 32; k++) {
                float zv = zbf[b * 32 + k];
                dh += zv * w_lh[col * 32 + k];
                dc += zv * w_lc[col * 32 + k];
            }
            if (col < 256) { h0p[b * 264 + col]         = __float2bfloat16(dh); cinitf[b * 256 + col]                 = dc; }
            else           { h1p[b * 264 + (col - 256)] = __float2bfloat16(dh); cinitf[8192 + b * 256 + (col - 256)] = dc; }
        }
    }
    __syncthreads();

    const int wv = tid >> 6, ln = tid & 63;
    const int l15 = ln & 15, lq = ln >> 4;
    const int lnoff = ln * 16;

    float c0r[2][2][4], c1r[2][2][4];
    {
        const float* cinitf = (const float*)smem;
        #pragma unroll
        for (int mt = 0; mt < 2; mt++)
            #pragma unroll
            for (int h = 0; h < 2; h++)
                #pragma unroll
                for (int r = 0; r < 4; r++) {
                    int m = mt * 16 + lq * 4 + r, u = wv * 32 + h * 16 + l15;
                    c0r[mt][h][r] = cinitf[m * 256 + u];
                    c1r[mt][h][r] = cinitf[8192 + m * 256 + u];
                }
    }
    __syncthreads();

    const float* bias0 = (const float*)(ws + OFF_B0);
    const float* bias1 = (const float*)(ws + OFF_B1);
    float bs0[8], bs1[8];
    #pragma unroll
    for (int q = 0; q < 8; q++) {
        int col = (q >> 1) * 256 + wv * 32 + (q & 1) * 16 + l15;
        bs0[q] = bias0[col];
        bs1[q] = bias1[col];
    }
    const int pc_nt = wv & 1, pc_mt = wv >> 1;
    const int pc_col = pc_nt * 16 + l15;
    const float bpj = (wv < 4 && pc_col < 20) ? b_proj[pc_col] : 0.0f;

    const char* wps_c = smem + SM_WPS;
    const char* h0c = smem + SM_H0;
    const char* h1c = smem + SM_H1;
    const char* xbc = smem + SM_XB;

    float* outp = out;

    const char* wgl   = ws + OFF_WSTR + wv * 1024 + lnoff;
    char*       ringb = smem + SM_RING + wv * 12288;
    const char* ringc = smem + SM_RING + wv * 12288 + lnoff;
    int sOff = 2 * 32768;
    int slS  = 2;
    int slR  = 0;

    f32x4 acc[8][2];

    auto doPanel = [&](const char* hsrc, int kt, bool isX, int qbase) {
        bf16x8 af0, af1;
        if (isX) {
            af0 = *(const bf16x8*)(xbc + l15 * 64 + lq * 16);
            af1 = *(const bf16x8*)(xbc + (16 + l15) * 64 + lq * 16);
        } else {
            af0 = *(const bf16x8*)(hsrc + l15 * 528 + kt * 64 + lq * 16);
            af1 = *(const bf16x8*)(hsrc + (16 + l15) * 528 + kt * 64 + lq * 16);
        }
        #pragma unroll
        for (int j = 0; j < 4; j++)
            stage16(wgl + (sOff + j * 8192), ringb + slS * 4096 + j * 1024);
        sOff += 32768; if (sOff >= WSTR_BYTES) sOff = 0;
        slS = (slS == 2) ? 0 : slS + 1;
        asm volatile("s_waitcnt vmcnt(8)" ::: "memory");
        __builtin_amdgcn_sched_barrier(0);
        const char* rb = ringc + slR * 4096;
        slR = (slR == 2) ? 0 : slR + 1;
        bf16x8 w0 = *(const bf16x8*)(rb);
        bf16x8 w1 = *(const bf16x8*)(rb + 1024);
        bf16x8 w2 = *(const bf16x8*)(rb + 2048);
        bf16x8 w3 = *(const bf16x8*)(rb + 3072);
        acc[qbase + 0][0] = __builtin_amdgcn_mfma_f32_16x16x32_bf16(af0, w0, acc[qbase + 0][0], 0, 0, 0);
        acc[qbase + 0][1] = __builtin_amdgcn_mfma_f32_16x16x32_bf16(af1, w0, acc[qbase + 0][1], 0, 0, 0);
        acc[qbase + 1][0] = __builtin_amdgcn_mfma_f32_16x16x32_bf16(af0, w1, acc[qbase + 1][0], 0, 0, 0);
        acc[qbase + 1][1] = __builtin_amdgcn_mfma_f32_16x16x32_bf16(af1, w1, acc[qbase + 1][1], 0, 0, 0);
        acc[qbase + 2][0] = __builtin_amdgcn_mfma_f32_16x16x32_bf16(af0, w2, acc[qbase + 2][0], 0, 0, 0);
        acc[qbase + 2][1] = __builtin_amdgcn_mfma_f32_16x16x32_bf16(af1, w2, acc[qbase + 2][1], 0, 0, 0);
        acc[qbase + 3][0] = __builtin_amdgcn_mfma_f32_16x16x32_bf16(af0, w3, acc[qbase + 3][0], 0, 0, 0);
        acc[qbase + 3][1] = __builtin_amdgcn_mfma_f32_16x16x32_bf16(af1, w3, acc[qbase + 3][1], 0, 0, 0);
    };

    auto phaseC = [&](int t) {
        f32x4 py = {bpj, bpj, bpj, bpj};
        #pragma unroll
        for (int kt = 0; kt < 8; kt++) {
            bf16x8 ah = *(const bf16x8*)(h1c + (pc_mt * 16 + l15) * 528 + kt * 64 + lq * 16);
            bf16x8 wf = *(const bf16x8*)(wps_c + pc_nt * 8192 + kt * 1024 + lnoff);
            py = __builtin_amdgcn_mfma_f32_16x16x32_bf16(ah, wf, py, 0, 0, 0);
        }
        if (pc_col < 20) {
            #pragma unroll
            for (int r = 0; r < 4; r++) {
                int row = pc_mt * 16 + lq * 4 + r;
                outp[((size_t)(b0 + row) * TT + (t - 1)) * DD + pc_col] = py[r];
                xbh[row * 32 + pc_col] = __float2bfloat16(py[r]);
            }
        }
    };

    #pragma unroll
    for (int j = 0; j < 4; j++) stage16(wgl + j * 8192,         ringb + j * 1024);
    #pragma unroll
    for (int j = 0; j < 4; j++) stage16(wgl + 32768 + j * 8192, ringb + 4096 + j * 1024);

    #pragma unroll 1
    for (int t = 0; t < TT; t++) {
        #pragma unroll
        for (int q = 0; q < 8; q++) {
            f32x4 v = {bs0[q], bs0[q], bs0[q], bs0[q]};
            acc[q][0] = v; acc[q][1] = v;
        }
        if (t > 0 && wv < 4) phaseC(t);
        #pragma unroll 1
        for (int uu = 0; uu < 7; uu++) {
            doPanel(h0c, uu, false, 0);
            doPanel(h0c, uu, false, 4);
        }
        BARRIER_LK;
        doPanel(h0c, 7, false, 0);
        doPanel(h0c, 7, false, 4);
        doPanel(xbc, 0, true,  0);
        doPanel(xbc, 0, true,  4);
        BARRIER_LK;

        #pragma unroll
        for (int mt = 0; mt < 2; mt++)
            #pragma unroll
            for (int h = 0; h < 2; h++)
                #pragma unroll
                for (int r = 0; r < 4; r++) {
                    float iv = acc[0 + h][mt][r], fv = acc[2 + h][mt][r];
                    float gv = acc[4 + h][mt][r], ov = acc[6 + h][mt][r];
                    float cn = sigf(fv) * c0r[mt][h][r] + sigf(iv) * tanhfast(gv);
                    float hn = sigf(ov) * tanhfast(cn);
                    c0r[mt][h][r] = cn;
                    h0p[(mt * 16 + lq * 4 + r) * 264 + wv * 32 + h * 16 + l15] = __float2bfloat16(hn);
                }
        BARRIER_LK;

        #pragma unroll
        for (int q = 0; q < 8; q++) {
            f32x4 v = {bs1[q], bs1[q], bs1[q], bs1[q]};
            acc[q][0] = v; acc[q][1] = v;
        }
        #pragma unroll 1
        for (int uu = 0; uu < 8; uu++) {
            doPanel(h0c, uu, false, 0);
            doPanel(h0c, uu, false, 4);
        }
        #pragma unroll 1
        for (int uu = 0; uu < 8; uu++) {
            doPanel(h1c, uu, false, 0);
            doPanel(h1c, uu, false, 4);
        }
        BARRIER_LK;

        #pragma unroll
        for (int mt = 0; mt < 2; mt++)
            #pragma unroll
            for (int h = 0; h < 2; h++)
                #pragma unroll
                for (int r = 0; r < 4; r++) {
                    float iv = acc[0 + h][mt][r], fv = acc[2 + h][mt][r];
                    float gv = acc[4 + h][mt][r], ov = acc[6 + h][mt][r];
                    float cn = sigf(fv) * c1r[mt][h][r] + sigf(iv) * tanhfast(gv);
                    float hn = sigf(ov) * tanhfast(cn);
                    c1r[mt][h][r] = cn;
                    h1p[(mt * 16 + lq * 4 + r) * 264 + wv * 32 + h * 16 + l15] = __float2bfloat16(hn);
                }
        BARRIER_LK;
    }

    if (wv < 4) phaseC(TT);
}

// ================= launcher =================

extern "C" void kernel_launch(void* const* d_in, const int* in_sizes, int n_in,
                              void* d_out, int out_size, void* d_ws, size_t ws_size,
                              hipStream_t stream) {
    const float* z      = (const float*)d_in[0];
    const float* w_lh   = (const float*)d_in[3];
    const float* b_lh   = (const float*)d_in[4];
    const float* w_lc   = (const float*)d_in[5];
    const float* b_lc   = (const float*)d_in[6];
    const float* w_ih0  = (const float*)d_in[7];
    const float* w_hh0  = (const float*)d_in[8];
    const float* b_ih0  = (const float*)d_in[9];
    const float* b_hh0  = (const float*)d_in[10];
    const float* w_ih1  = (const float*)d_in[11];
    const float* w_hh1  = (const float*)d_in[12];
    const float* b_ih1  = (const float*)d_in[13];
    const float* b_hh1  = (const float*)d_in[14];
    const float* w_proj = (const float*)d_in[15];
    const float* b_proj = (const float*)d_in[16];
    char* ws = (char*)d_ws;
    float* out = (float*)d_out;

    if (ws_size >= (size_t)WS_NEED_QUAD) {
        prep_quad<<<3242, 256, 0, stream>>>(w_ih0, w_hh0, w_ih1, w_hh1, w_proj,
                                            b_ih0, b_hh0, b_ih1, b_hh1, ws);
        decoder_quad<<<256, 256, 0, stream>>>(z, w_lh, b_lh, w_lc, b_lc, b_proj, ws, out);
    } else {
        prep_solo<<<3240, 256, 0, stream>>>(w_ih0, w_hh0, w_ih1, w_hh1, w_proj,
                                            b_ih0, b_hh0, b_ih1, b_hh1, ws);
        decoder_solo<<<64, 512, 0, stream>>>(z, w_lh, b_lh, w_lc, b_lc, b_proj, ws, out);
    }
}